// Round 15
// baseline (462.338 us; speedup 1.0000x reference)
//
#include <hip/hip_runtime.h>

// ---------------------------------------------------------------------------
// LowFreqSparseAttention: qkv 1x1conv -> l2norm(q,k) -> S=QK^T*scale ->
// top-k(k=N/2) mask -> softmax -> PV -> proj 1x1conv -> GroupNorm(32 groups).
// B=1, C=256, H=W=64 -> N=4096, 8 heads, hd=32, k_sel=2048.
//
// R28 = R27 with launch bounds back to (256,5) AND phase-2 kv loads split
// into 2+2 batches (sched_barrier(0) between) to fit the 102-VGPR cap
// WITHOUT spill.
// Measured so far: spill @ 4 blocks (R26, cap 102, 16 live kv) = 371us;
// no-spill @ 3 blocks (R27, cap 128) = 375us. The unclaimed regime is
// no-spill @ 4-5 blocks: peak demand must drop to <=102.
// Phase-2 peak: kr 64 + kv batch 8 (was 16) + q 4 + addr ~12 ~= 88 < 102.
// The sched_barrier's PURPOSE here is to cap in-flight loads at 2 (reg
// pressure), trading MLP that 16-20 resident waves/CU already cover
// (200cyc L2 latency vs 64cyc compute per half-iter x 4-5 waves/SIMD).
// Predict: WRITE ~4MB (no-spill tripwire), occ ~50-62%, attn ~340-360,
// total ~420-435. WRITE explodes => demand model wrong; attn flat ~370
// at 50% occ clean => levers exhausted -> structural floor next.
// ---------------------------------------------------------------------------

#define NTOK 4096
#define HD 32
#define NHEADS 8
#define KSEL 2048
#define SCALE 0.17677669529663689f   // 32^-0.5  (folded into l2norm_q)
#define LOG2C 7.73937f               // log2(255 / e^0.1767767)

typedef __fp16 f16x2 __attribute__((ext_vector_type(2)));

#define USE_DOT2 (__has_builtin(__builtin_amdgcn_fdot2) && \
                  __has_builtin(__builtin_amdgcn_cvt_pkrtz))

// ---- helpers --------------------------------------------------------------

__device__ __forceinline__ unsigned fkey(float f) {
  unsigned b = __float_as_uint(f);
  return (b & 0x80000000u) ? ~b : (b | 0x80000000u);
}
__device__ __forceinline__ float unfkey(unsigned k) {
  unsigned b = (k & 0x80000000u) ? (k ^ 0x80000000u) : ~k;
  return __uint_as_float(b);
}
__device__ __forceinline__ unsigned rfl_u(unsigned x) {  // force SGPR
  return __builtin_amdgcn_readfirstlane(x);
}
__device__ __forceinline__ f16x2 asv2h(unsigned u) {
  union { unsigned u; f16x2 h; } c; c.u = u; return c.h;
}
__device__ __forceinline__ unsigned asu32(f16x2 h) {
  union { f16x2 h; unsigned u; } c; c.h = h; return c.u;
}
// regula-falsi probe in key space, clamped to (klo, khi]
__device__ __forceinline__ unsigned probe_rf(unsigned klo, unsigned khi,
                                             float xlo, float xhi,
                                             int clo, int chi) {
  float t = xlo + (xhi - xlo) * ((float)(clo - KSEL) / (float)(clo - chi));
  unsigned k = fkey(t);
  if (k <= klo) k = klo + 1u;
  if (k > khi) k = khi;
  return k;
}

// ---- kernel 1/4: GEMM  C[M][4096] = A[M][256] * B[256][4096] --------------
// SCATTER: M=768 -> Q [h][n][d], KT [h][d][n] (transposed!), V [h][n][d].
// else:    M=256 -> plain row-major C0.

template <bool SCATTER>
__global__ __launch_bounds__(256) void gemm_k256(
    const float* __restrict__ A, const float* __restrict__ B,
    float* __restrict__ C0, float* __restrict__ C1, float* __restrict__ C2) {
  __shared__ float Wt[64][17];   // +1 pad: avoid 16-way bank conflict
  __shared__ float Xt[16][64];

  const int tid = threadIdx.x;
  const int tx = tid & 15, ty = tid >> 4;
  const int o0 = blockIdx.y * 64, n0 = blockIdx.x * 64;

  const int wr = tid >> 2, wc = (tid & 3) << 2;   // W-tile 64x16 loader
  const int xr = tid >> 4, xc = (tid & 15) << 2;  // X-tile 16x64 loader

  float4 acc[4];
#pragma unroll
  for (int i = 0; i < 4; ++i) acc[i] = make_float4(0.f, 0.f, 0.f, 0.f);

  for (int k0 = 0; k0 < 256; k0 += 16) {
    float4 wv = *(const float4*)(A + (o0 + wr) * 256 + k0 + wc);
    float4 xv = *(const float4*)(B + (k0 + xr) * 4096 + n0 + xc);
    Wt[wr][wc + 0] = wv.x; Wt[wr][wc + 1] = wv.y;
    Wt[wr][wc + 2] = wv.z; Wt[wr][wc + 3] = wv.w;
    *(float4*)&Xt[xr][xc] = xv;
    __syncthreads();
#pragma unroll
    for (int kk = 0; kk < 16; ++kk) {
      float4 b = *(const float4*)&Xt[kk][tx << 2];
#pragma unroll
      for (int i = 0; i < 4; ++i) {
        float a = Wt[(ty << 2) + i][kk];
        acc[i].x += a * b.x; acc[i].y += a * b.y;
        acc[i].z += a * b.z; acc[i].w += a * b.w;
      }
    }
    __syncthreads();
  }

  if (SCATTER) {
#pragma unroll
    for (int i = 0; i < 4; ++i) {
      int o = o0 + (ty << 2) + i;
      int which = o >> 8, rem = o & 255;
      int h = rem >> 5, d = rem & 31;
      int n = n0 + (tx << 2);
      if (which == 1) {
        // KT[h][d][n..n+3]: contiguous float4
        *(float4*)(C1 + h * (HD * NTOK) + d * NTOK + n) = acc[i];
      } else {
        float* dst = (which == 0) ? C0 : C2;
        int base = h * (NTOK * HD) + d;
        dst[base + (n + 0) * HD] = acc[i].x;
        dst[base + (n + 1) * HD] = acc[i].y;
        dst[base + (n + 2) * HD] = acc[i].z;
        dst[base + (n + 3) * HD] = acc[i].w;
      }
    }
  } else {
#pragma unroll
    for (int i = 0; i < 4; ++i) {
      int o = o0 + (ty << 2) + i;
      *(float4*)(C0 + o * 4096 + n0 + (tx << 2)) = acc[i];
    }
  }
}

// ---- kernel 2a: l2norm Q rows [h][n][32], folds SCALE ---------------------

__global__ __launch_bounds__(256) void l2norm_q(float* __restrict__ Q) {
  const int tid = threadIdx.x;
  const int p = blockIdx.x * 8 + (tid >> 5);  // (head*4096+n) row index
  const int d = tid & 31;
  const int idx = p * HD + d;
  float v = Q[idx];
  float ss = v * v;
#pragma unroll
  for (int m = 16; m >= 1; m >>= 1) ss += __shfl_xor(ss, m, 32);
  float nrm = sqrtf(ss);
  Q[idx] = v * SCALE / fmaxf(nrm, 1e-12f);
}

// ---- kernel 2b: l2norm KT columns + fp16 d-pair pack (in place) -----------
// Reads KT[h][d][n] (fp32, all 32 d at fixed n), normalizes, writes packed
// fp16 pairs K16[h][d2][n] = (k[2d2],k[2d2+1]) over KT's first 16 rows.
// Aliasing is column-local (thread reads its column fully before storing).

__global__ __launch_bounds__(256) void l2norm_kt_pack(float* __restrict__ KT) {
  const int n = blockIdx.x * 256 + threadIdx.x;
  float* P = KT + blockIdx.y * (HD * NTOK) + n;
  float v[HD];
  float ss = 0.f;
#pragma unroll
  for (int d = 0; d < HD; ++d) {
    v[d] = P[d * NTOK];          // coalesced across lanes
    ss += v[d] * v[d];
  }
  float inv = 1.f / fmaxf(sqrtf(ss), 1e-12f);
  unsigned* O = (unsigned*)P;    // in-place: rows 0..15 as pair words
#pragma unroll
  for (int d2 = 0; d2 < 16; ++d2) {
#if USE_DOT2
    O[d2 * NTOK] = asu32(
        __builtin_amdgcn_cvt_pkrtz(v[2 * d2] * inv, v[2 * d2 + 1] * inv));
#else
    f16x2 p; p[0] = (__fp16)(v[2 * d2] * inv); p[1] = (__fp16)(v[2 * d2 + 1] * inv);
    O[d2 * NTOK] = asu32(p);
#endif
  }
}

// ---- kernel 3: fused attention (4 rows per block, column-partitioned) -----
// phase1: stage 4 q rows (fp32) + pack fp16 q d-pairs into LDS (once).
// phase2: thread tid owns cols {g*1024 + tid*4 + t}; 16 d2-iters of
//         {2+2 batched b128 K-pair loads + 4 broadcast b32 q-pair reads +
//          64 v_dot2_f32_f16} -> kr[4][16] fp32. 2+2 split caps live kv
//         at 8 regs so the 5-wave VGPR cap (102) holds without spill.
// phase3: hybrid selection (R19 window: RF while it<8 && width>65536, then
//         ulp bisection). Counts readfirstlane'd -> state SALU/SGPR;
//         per-row done-guards skip converged ballots.
// phase4: u8 weights packed 4 rows/col -> ONE ds_write_b128 per 4 cols;
//         exact integer denominators, block-reduced.  (R19 verbatim)
// phase5: PV scalar u8 (R19 verbatim, unroll 4).

__global__ __launch_bounds__(256, 5) void attn_kernel(
    const float* __restrict__ Q, const float* __restrict__ KT,
    const float* __restrict__ V, float* __restrict__ AO) {
  __shared__ __align__(16) unsigned char wtsT[NTOK][4];   // 16 KB, [m][row]
  __shared__ float qs[128];
  __shared__ unsigned qs2u[4][16];                        // fp16 q d-pairs
  __shared__ float pvred[4 * 8 * 4 * 4];                  // 2 KB
  __shared__ unsigned ired[2][4][2];                      // bisection dbuf
  __shared__ unsigned dred[4][4];                         // denom partials

  const int tid = threadIdx.x;
  const int wv = tid >> 6, lane = tid & 63;
  const int head = blockIdx.x & 7;          // head == blockIdx%8 -> XCD-pinned
  const int n0 = (blockIdx.x >> 3) << 2;

  const float* Qh = Q + head * (NTOK * HD);
  const float* KTh = KT + head * (HD * NTOK);
  const float* Vh = V + head * (NTOK * HD);

  // phase 1: stage the block's 4 q rows (already *SCALE from l2norm_q),
  // then pack fp16 d-pairs (once per block).
  if (tid < 128) qs[tid] = Qh[n0 * HD + tid];
  __syncthreads();
  if (tid < 64) {
    const int r = tid >> 4, d2 = tid & 15;
#if USE_DOT2
    qs2u[r][d2] = asu32(__builtin_amdgcn_cvt_pkrtz(
        qs[r * HD + (d2 << 1)], qs[r * HD + (d2 << 1) + 1]));
#else
    f16x2 p; p[0] = (__fp16)qs[r * HD + (d2 << 1)];
    p[1] = (__fp16)qs[r * HD + (d2 << 1) + 1];
    qs2u[r][d2] = asu32(p);
#endif
  }
  __syncthreads();

  // phase 2: kr[r][g*4+t] = score(row r, col g*1024 + tid*4 + t) via dot2
  // over d-pairs. Each K pair-word read by exactly ONE thread of the block.
  float kr[4][16];
#pragma unroll
  for (int r = 0; r < 4; ++r)
#pragma unroll
    for (int j = 0; j < 16; ++j) kr[r][j] = 0.f;

  const int cb = tid << 2;
  const unsigned* k16 = (const unsigned*)KTh + cb;   // [16][NTOK] pair words
#pragma unroll 1
  for (int d2 = 0; d2 < 16; ++d2) {
    const unsigned* kp = k16 + d2 * NTOK;
    const unsigned qu0 = qs2u[0][d2], qu1 = qs2u[1][d2];
    const unsigned qu2 = qs2u[2][d2], qu3 = qs2u[3][d2];
#if USE_DOT2
    const f16x2 q0 = asv2h(qu0), q1 = asv2h(qu1);
    const f16x2 q2 = asv2h(qu2), q3 = asv2h(qu3);
#define DOT8(r, qv, kva, kvb, j0)                                            \
    kr[r][(j0)+0] = __builtin_amdgcn_fdot2(qv, asv2h((kva).x), kr[r][(j0)+0], false); \
    kr[r][(j0)+1] = __builtin_amdgcn_fdot2(qv, asv2h((kva).y), kr[r][(j0)+1], false); \
    kr[r][(j0)+2] = __builtin_amdgcn_fdot2(qv, asv2h((kva).z), kr[r][(j0)+2], false); \
    kr[r][(j0)+3] = __builtin_amdgcn_fdot2(qv, asv2h((kva).w), kr[r][(j0)+3], false); \
    kr[r][(j0)+4] = __builtin_amdgcn_fdot2(qv, asv2h((kvb).x), kr[r][(j0)+4], false); \
    kr[r][(j0)+5] = __builtin_amdgcn_fdot2(qv, asv2h((kvb).y), kr[r][(j0)+5], false); \
    kr[r][(j0)+6] = __builtin_amdgcn_fdot2(qv, asv2h((kvb).z), kr[r][(j0)+6], false); \
    kr[r][(j0)+7] = __builtin_amdgcn_fdot2(qv, asv2h((kvb).w), kr[r][(j0)+7], false);
    {
      const uint4 kv0 = *(const uint4*)(kp);
      const uint4 kv1 = *(const uint4*)(kp + 1024);
      DOT8(0, q0, kv0, kv1, 0) DOT8(1, q1, kv0, kv1, 0)
      DOT8(2, q2, kv0, kv1, 0) DOT8(3, q3, kv0, kv1, 0)
    }
    __builtin_amdgcn_sched_barrier(0);   // cap live kv at 8 regs (102-cap)
    {
      const uint4 kv2 = *(const uint4*)(kp + 2048);
      const uint4 kv3 = *(const uint4*)(kp + 3072);
      DOT8(0, q0, kv2, kv3, 8) DOT8(1, q1, kv2, kv3, 8)
      DOT8(2, q2, kv2, kv3, 8) DOT8(3, q3, kv2, kv3, 8)
    }
#undef DOT8
#else
    // fallback: decode pairs and FMA (compile insurance; fdot2 proven on HW)
#define DOTF(r, qu, kk0, kk1, j0)                                            \
    {                                                                        \
      const f16x2 qq = asv2h(qu);                                            \
      const float qa = (float)qq[0], qb = (float)qq[1];                      \
      const unsigned kk[8] = {(kk0).x, (kk0).y, (kk0).z, (kk0).w,            \
                              (kk1).x, (kk1).y, (kk1).z, (kk1).w};           \
      _Pragma("unroll")                                                      \
      for (int j = 0; j < 8; ++j) {                                          \
        const f16x2 kh = asv2h(kk[j]);                                       \
        kr[r][(j0) + j] += qa * (float)kh[0] + qb * (float)kh[1];            \
      }                                                                      \
    }
    {
      const uint4 kv0 = *(const uint4*)(kp);
      const uint4 kv1 = *(const uint4*)(kp + 1024);
      DOTF(0, qu0, kv0, kv1, 0) DOTF(1, qu1, kv0, kv1, 0)
      DOTF(2, qu2, kv0, kv1, 0) DOTF(3, qu3, kv0, kv1, 0)
    }
    {
      const uint4 kv2 = *(const uint4*)(kp + 2048);
      const uint4 kv3 = *(const uint4*)(kp + 3072);
      DOTF(0, qu0, kv2, kv3, 8) DOTF(1, qu1, kv2, kv3, 8)
      DOTF(2, qu2, kv2, kv3, 8) DOTF(3, qu3, kv2, kv3, 8)
    }
#undef DOTF
#endif
  }

  // phase 3: hybrid selection per row (R19 schedule). Bracket invariant
  // (key space): count(klo) >= KSEL, answer in [klo, khi]. RF probe while
  // it<8 && width>65536; ulp midpoint after. Exit on count==KSEL (kept set
  // == top-k of the COMPUTED scores; ties make the count skip KSEL so
  // ==KSEL is tie-free) or klo==khi (exact kth key).
  // |scores| <= 0.1768 < 0.25, so anchors (-0.25 -> 4096, +0.25 -> 0).
  // State block-uniform; counts readfirstlane'd -> SGPR/SALU resident.
  unsigned klo0 = 0x417FFFFFu, khi0 = 0xBE800000u;  // fkey(-.25), fkey(.25)
  unsigned klo1 = 0x417FFFFFu, khi1 = 0xBE800000u;
  unsigned klo2 = 0x417FFFFFu, khi2 = 0xBE800000u;
  unsigned klo3 = 0x417FFFFFu, khi3 = 0xBE800000u;
  float xlo0 = -0.25f, xhi0 = 0.25f, xlo1 = -0.25f, xhi1 = 0.25f;
  float xlo2 = -0.25f, xhi2 = 0.25f, xlo3 = -0.25f, xhi3 = 0.25f;
  int clo0 = NTOK, chi0 = 0, clo1 = NTOK, chi1 = 0;
  int clo2 = NTOK, chi2 = 0, clo3 = NTOK, chi3 = 0;
  bool dn0 = false, dn1 = false, dn2 = false, dn3 = false;
  int slot = 0;
#pragma unroll 1
  for (int it = 0; it < 40; ++it) {
    unsigned m0 = dn0 ? klo0
        : ((it < 8 && (khi0 - klo0) > 65536u)
               ? rfl_u(probe_rf(klo0, khi0, xlo0, xhi0, clo0, chi0))
               : klo0 + ((khi0 - klo0 + 1u) >> 1));
    unsigned m1 = dn1 ? klo1
        : ((it < 8 && (khi1 - klo1) > 65536u)
               ? rfl_u(probe_rf(klo1, khi1, xlo1, xhi1, clo1, chi1))
               : klo1 + ((khi1 - klo1 + 1u) >> 1));
    unsigned m2 = dn2 ? klo2
        : ((it < 8 && (khi2 - klo2) > 65536u)
               ? rfl_u(probe_rf(klo2, khi2, xlo2, xhi2, clo2, chi2))
               : klo2 + ((khi2 - klo2 + 1u) >> 1));
    unsigned m3 = dn3 ? klo3
        : ((it < 8 && (khi3 - klo3) > 65536u)
               ? rfl_u(probe_rf(klo3, khi3, xlo3, xhi3, clo3, chi3))
               : klo3 + ((khi3 - klo3 + 1u) >> 1));
    unsigned c0 = 0, c1 = 0, c2 = 0, c3 = 0;
    if (!dn0) {
      const float f0 = unfkey(m0);
#pragma unroll
      for (int j = 0; j < 16; ++j) c0 += __popcll(__ballot(kr[0][j] >= f0));
    }
    if (!dn1) {
      const float f1 = unfkey(m1);
#pragma unroll
      for (int j = 0; j < 16; ++j) c1 += __popcll(__ballot(kr[1][j] >= f1));
    }
    if (!dn2) {
      const float f2 = unfkey(m2);
#pragma unroll
      for (int j = 0; j < 16; ++j) c2 += __popcll(__ballot(kr[2][j] >= f2));
    }
    if (!dn3) {
      const float f3 = unfkey(m3);
#pragma unroll
      for (int j = 0; j < 16; ++j) c3 += __popcll(__ballot(kr[3][j] >= f3));
    }
    if (lane == 0) {
      ired[slot][wv][0] = c0 | (c1 << 16);
      ired[slot][wv][1] = c2 | (c3 << 16);
    }
    __syncthreads();
    unsigned a01 = rfl_u(ired[slot][0][0] + ired[slot][1][0] +
                         ired[slot][2][0] + ired[slot][3][0]);
    unsigned a23 = rfl_u(ired[slot][0][1] + ired[slot][1][1] +
                         ired[slot][2][1] + ired[slot][3][1]);
    slot ^= 1;
    int C0 = (int)(a01 & 0xFFFFu), C1 = (int)(a01 >> 16);
    int C2 = (int)(a23 & 0xFFFFu), C3 = (int)(a23 >> 16);
#define BUPD(C, klo, khi, xlo, xhi, clo, chi, dn, mk)                        \
    if (!dn) {                                                               \
      if (C == KSEL) { klo = mk; dn = true; }                                \
      else if (C > KSEL) { klo = mk; xlo = unfkey(mk); clo = C; }            \
      else { khi = mk - 1u; xhi = unfkey(mk); chi = C; }                     \
      if (klo >= khi) dn = true;                                             \
    }
    BUPD(C0, klo0, khi0, xlo0, xhi0, clo0, chi0, dn0, m0)
    BUPD(C1, klo1, khi1, xlo1, xhi1, clo1, chi1, dn1, m1)
    BUPD(C2, klo2, khi2, xlo2, xhi2, clo2, chi2, dn2, m2)
    BUPD(C3, klo3, khi3, xlo3, xhi3, clo3, chi3, dn3, m3)
#undef BUPD
    if (dn0 && dn1 && dn2 && dn3) break;   // uniform across block
  }
  const float tf0 = unfkey(klo0), tf1 = unfkey(klo1);
  const float tf2 = unfkey(klo2), tf3 = unfkey(klo3);

  // phase 4: u8 weights, 4 rows packed per column, b128 per 4 columns.
  // u = rint(exp(s) * 255/e^smax) in [179,255] kept, 0 masked. (R19)
  unsigned id0 = 0, id1 = 0, id2 = 0, id3 = 0;
#pragma unroll
  for (int g = 0; g < 4; ++g) {
    unsigned pk[4];
#pragma unroll
    for (int t = 0; t < 4; ++t) {
      const int j = (g << 2) + t;
      float s0 = kr[0][j], s1 = kr[1][j], s2 = kr[2][j], s3 = kr[3][j];
      unsigned u0 = (s0 >= tf0) ? (unsigned)rintf(exp2f(__builtin_fmaf(s0, 1.44269504f, LOG2C))) : 0u;
      unsigned u1 = (s1 >= tf1) ? (unsigned)rintf(exp2f(__builtin_fmaf(s1, 1.44269504f, LOG2C))) : 0u;
      unsigned u2 = (s2 >= tf2) ? (unsigned)rintf(exp2f(__builtin_fmaf(s2, 1.44269504f, LOG2C))) : 0u;
      unsigned u3 = (s3 >= tf3) ? (unsigned)rintf(exp2f(__builtin_fmaf(s3, 1.44269504f, LOG2C))) : 0u;
      id0 += u0; id1 += u1; id2 += u2; id3 += u3;
      pk[t] = u0 | (u1 << 8) | (u2 << 16) | (u3 << 24);
    }
    const int col = (g << 10) + cb;            // addr = col*4, 16B-aligned
    *(uint4*)&wtsT[col][0] = make_uint4(pk[0], pk[1], pk[2], pk[3]);
  }
  // exact integer denominators: wave-reduce then cross-wave sum
#pragma unroll
  for (int s = 1; s < 64; s <<= 1) {
    id0 += __shfl_xor(id0, s); id1 += __shfl_xor(id1, s);
    id2 += __shfl_xor(id2, s); id3 += __shfl_xor(id3, s);
  }
  if (lane == 0) *(uint4*)&dred[wv][0] = make_uint4(id0, id1, id2, id3);
  __syncthreads();  // wtsT + dred visible to all
  const float dnm0 = (float)(dred[0][0] + dred[1][0] + dred[2][0] + dred[3][0]);
  const float dnm1 = (float)(dred[0][1] + dred[1][1] + dred[2][1] + dred[3][1]);
  const float dnm2 = (float)(dred[0][2] + dred[1][2] + dred[2][2] + dred[3][2]);
  const float dnm3 = (float)(dred[0][3] + dred[1][3] + dred[2][3] + dred[3][3]);

  // phase 5: PV with integer weights (R19). wave wv covers m in
  // [wv*1024, +1024); unroll 4.
  const int slot5 = lane & 7, mg = lane >> 3;
  const int mbase = wv << 10;
  float av[4][4];
#pragma unroll
  for (int r = 0; r < 4; ++r)
#pragma unroll
    for (int c = 0; c < 4; ++c) av[r][c] = 0.f;

#pragma unroll 4
  for (int ii = 0; ii < 128; ++ii) {
    const int m = mbase + (ii << 3) + mg;
    unsigned wq = *(const unsigned*)&wtsT[m][0];   // one b32: rows 0..3
    float4 v = *(const float4*)(Vh + m * HD + (slot5 << 2));
    float w0 = (float)(wq & 0xFFu);          // v_cvt_f32_ubyte0
    float w1 = (float)((wq >> 8) & 0xFFu);   // v_cvt_f32_ubyte1
    float w2 = (float)((wq >> 16) & 0xFFu);  // v_cvt_f32_ubyte2
    float w3 = (float)(wq >> 24);            // v_cvt_f32_ubyte3
    av[0][0] += w0 * v.x; av[0][1] += w0 * v.y; av[0][2] += w0 * v.z; av[0][3] += w0 * v.w;
    av[1][0] += w1 * v.x; av[1][1] += w1 * v.y; av[1][2] += w1 * v.z; av[1][3] += w1 * v.w;
    av[2][0] += w2 * v.x; av[2][1] += w2 * v.y; av[2][2] += w2 * v.z; av[2][3] += w2 * v.w;
    av[3][0] += w3 * v.x; av[3][1] += w3 * v.y; av[3][2] += w3 * v.z; av[3][3] += w3 * v.w;
  }
  // reduce over mg (lane bits 3..5)
#pragma unroll
  for (int r = 0; r < 4; ++r)
#pragma unroll
    for (int c = 0; c < 4; ++c) {
      float x = av[r][c];
      x += __shfl_xor(x, 8); x += __shfl_xor(x, 16); x += __shfl_xor(x, 32);
      av[r][c] = x;
    }
  if (mg == 0) {
#pragma unroll
    for (int r = 0; r < 4; ++r)
#pragma unroll
      for (int c = 0; c < 4; ++c)
        pvred[(((wv << 3) + slot5) * 4 + r) * 4 + c] = av[r][c];
  }
  __syncthreads();

  if (tid < 128) {
    const int r = tid >> 5, d = tid & 31;
    const int sl = d >> 2, c = d & 3;
    float val = 0.f;
#pragma unroll
    for (int w = 0; w < 4; ++w) val += pvred[(((w << 3) + sl) * 4 + r) * 4 + c];
    float dn = (r == 0) ? dnm0 : (r == 1) ? dnm1 : (r == 2) ? dnm2 : dnm3;
    val /= dn;
    AO[(head * HD + d) * NTOK + n0 + r] = val;  // [C][N] for proj GEMM
  }
}

// ---- kernel 5: GroupNorm stats (32 groups of 8 ch x 4096 = 32768 vals) ----

__global__ __launch_bounds__(256) void gn_stats(const float* __restrict__ O,
                                                float* __restrict__ ST) {
  const int g = blockIdx.x, tid = threadIdx.x;
  const float4* p4 = (const float4*)(O + g * 32768);
  float s = 0.f, ss = 0.f;
  for (int i = tid; i < 8192; i += 256) {
    float4 v = p4[i];
    s += (v.x + v.y) + (v.z + v.w);
    ss += (v.x * v.x + v.y * v.y) + (v.z * v.z + v.w * v.w);
  }
#pragma unroll
  for (int m = 1; m < 64; m <<= 1) {
    s += __shfl_xor(s, m);
    ss += __shfl_xor(ss, m);
  }
  __shared__ float rs[4], rss[4];
  if ((tid & 63) == 0) { rs[tid >> 6] = s; rss[tid >> 6] = ss; }
  __syncthreads();
  if (tid == 0) {
    float S = rs[0] + rs[1] + rs[2] + rs[3];
    float SS = rss[0] + rss[1] + rss[2] + rss[3];
    float mean = S * (1.f / 32768.f);
    float var = SS * (1.f / 32768.f) - mean * mean;
    ST[g * 2] = mean;
    ST[g * 2 + 1] = rsqrtf(var + 1e-6f);
  }
}

// ---- kernel 6: GroupNorm apply (in place on d_out) ------------------------
// Indexes FLOAT4s: total 1048576/4 = 262144 -> grid 1024 x 256.

__global__ __launch_bounds__(256) void gn_apply(float* __restrict__ O,
                                                const float* __restrict__ ST,
                                                const float* __restrict__ gamma,
                                                const float* __restrict__ beta) {
  const int i4 = blockIdx.x * 256 + threadIdx.x;  // float4 index
  const int c = i4 >> 10, g = c >> 3;
  const float a = ST[g * 2 + 1] * gamma[c];
  const float b = beta[c] - ST[g * 2] * a;
  float4 v = *(float4*)(O + (i4 << 2));
  v.x = v.x * a + b; v.y = v.y * a + b; v.z = v.z * a + b; v.w = v.w * a + b;
  *(float4*)(O + (i4 << 2)) = v;
}

// ---- launch ---------------------------------------------------------------

extern "C" void kernel_launch(void* const* d_in, const int* in_sizes, int n_in,
                              void* d_out, int out_size, void* d_ws,
                              size_t ws_size, hipStream_t stream) {
  const float* x = (const float*)d_in[0];       // [256][4096]
  const float* w_qkv = (const float*)d_in[1];   // [768][256]
  const float* w_proj = (const float*)d_in[2];  // [256][256]
  const float* gamma = (const float*)d_in[3];   // [256]
  const float* beta = (const float*)d_in[4];    // [256]
  float* out = (float*)d_out;                   // [256][4096]

  float* Q = (float*)d_ws;          // [8][4096][32]
  float* KT = Q + 1048576;          // [8][32][4096] fp32 -> fp16 pairs in place
  float* V = KT + 1048576;          // [8][4096][32]
  float* AO = V + 1048576;          // [256][4096]
  float* ST = AO + 1048576;         // [32][2]

  gemm_k256<true><<<dim3(64, 12), 256, 0, stream>>>(w_qkv, x, Q, KT, V);
  l2norm_q<<<4096, 256, 0, stream>>>(Q);
  l2norm_kt_pack<<<dim3(16, 8), 256, 0, stream>>>(KT);
  attn_kernel<<<8192, 256, 0, stream>>>(Q, KT, V, AO);
  gemm_k256<false><<<dim3(64, 4), 256, 0, stream>>>(w_proj, AO, out, nullptr, nullptr);
  gn_stats<<<32, 256, 0, stream>>>(out, ST);
  gn_apply<<<1024, 256, 0, stream>>>(out, ST, gamma, beta);
}

// Round 16
// 444.276 us; speedup vs baseline: 1.0407x; 1.0407x over previous
//
#include <hip/hip_runtime.h>

// ---------------------------------------------------------------------------
// LowFreqSparseAttention: qkv 1x1conv -> l2norm(q,k) -> S=QK^T*scale ->
// top-k(k=N/2) mask -> softmax -> PV -> proj 1x1conv -> GroupNorm(32 groups).
// B=1, C=256, H=W=64 -> N=4096, 8 heads, hd=32, k_sel=2048.
//
// R29 = R26 (371us: dot2-K phase2, best) + convert-once pk_fma PV.
// R28 post-mortem: {spill x occupancy} grid all lands 371-376 -> kernel is
// VALU-ISSUE bound; only instruction removal has paid (dot2 phase2 -40us).
// Phase 5 is now the biggest issue block (~23 insts/m x 128). Make it
// convert-once fp16 (the twice-learned rule):
//  * QKV GEMM writes V as fp16 V16[h][m][d] (numerics validated R22).
//  * phase4 writes fp16 weights wts2[m][4] in LDS (u8-scale ints exact;
//    cvt_pkrtz exact on integers). LDS 36KB -> still 4 blocks/CU.
//  * phase5 per m: 1 ds_read_b64 (4 w fp16) + 1 global b64 (4 v fp16) +
//    4 v_perm_b32 (dup w -> (w,w)) + 8 v_pk_fma_f16  ~= 15 insts vs 23.
//    fp16 accumulate: lane partials <=~1500, 128 adds -> ~1e-5 of output.
//    Integer denominators unchanged (exact).
// Launch (256,5) as R26. Predict: attn ~335-355, total ~410-430,
// absmax <= ~0.0625. Pre-committed: absmax fail or attn >= 370 -> revert
// R26, declare structural floor.
// ---------------------------------------------------------------------------

#define NTOK 4096
#define HD 32
#define NHEADS 8
#define KSEL 2048
#define SCALE 0.17677669529663689f   // 32^-0.5  (folded into l2norm_q)
#define LOG2C 7.73937f               // log2(255 / e^0.1767767)

typedef __fp16 f16x2 __attribute__((ext_vector_type(2)));

#define USE_DOT2 (__has_builtin(__builtin_amdgcn_fdot2) && \
                  __has_builtin(__builtin_amdgcn_cvt_pkrtz))

// ---- helpers --------------------------------------------------------------

__device__ __forceinline__ unsigned fkey(float f) {
  unsigned b = __float_as_uint(f);
  return (b & 0x80000000u) ? ~b : (b | 0x80000000u);
}
__device__ __forceinline__ float unfkey(unsigned k) {
  unsigned b = (k & 0x80000000u) ? (k ^ 0x80000000u) : ~k;
  return __uint_as_float(b);
}
__device__ __forceinline__ unsigned rfl_u(unsigned x) {  // force SGPR
  return __builtin_amdgcn_readfirstlane(x);
}
__device__ __forceinline__ f16x2 asv2h(unsigned u) {
  union { unsigned u; f16x2 h; } c; c.u = u; return c.h;
}
__device__ __forceinline__ unsigned asu32(f16x2 h) {
  union { f16x2 h; unsigned u; } c; c.h = h; return c.u;
}
__device__ __forceinline__ unsigned dup_lo16(unsigned x) {  // (lo,lo)
#if __has_builtin(__builtin_amdgcn_perm)
  return __builtin_amdgcn_perm(x, x, 0x05040504u);
#else
  return (x & 0xFFFFu) | (x << 16);
#endif
}
__device__ __forceinline__ unsigned dup_hi16(unsigned x) {  // (hi,hi)
#if __has_builtin(__builtin_amdgcn_perm)
  return __builtin_amdgcn_perm(x, x, 0x07060706u);
#else
  return (x & 0xFFFF0000u) | (x >> 16);
#endif
}
// regula-falsi probe in key space, clamped to (klo, khi]
__device__ __forceinline__ unsigned probe_rf(unsigned klo, unsigned khi,
                                             float xlo, float xhi,
                                             int clo, int chi) {
  float t = xlo + (xhi - xlo) * ((float)(clo - KSEL) / (float)(clo - chi));
  unsigned k = fkey(t);
  if (k <= klo) k = klo + 1u;
  if (k > khi) k = khi;
  return k;
}

// ---- kernel 1/4: GEMM  C[M][4096] = A[M][256] * B[256][4096] --------------
// SCATTER: M=768 -> Q [h][n][d] fp32, KT [h][d][n] fp32 (transposed),
//          V16 [h][n][d] FP16 (scattered 2B stores).
// else:    M=256 -> plain row-major C0.

template <bool SCATTER>
__global__ __launch_bounds__(256) void gemm_k256(
    const float* __restrict__ A, const float* __restrict__ B,
    float* __restrict__ C0, float* __restrict__ C1, float* __restrict__ C2) {
  __shared__ float Wt[64][17];   // +1 pad: avoid 16-way bank conflict
  __shared__ float Xt[16][64];

  const int tid = threadIdx.x;
  const int tx = tid & 15, ty = tid >> 4;
  const int o0 = blockIdx.y * 64, n0 = blockIdx.x * 64;

  const int wr = tid >> 2, wc = (tid & 3) << 2;   // W-tile 64x16 loader
  const int xr = tid >> 4, xc = (tid & 15) << 2;  // X-tile 16x64 loader

  float4 acc[4];
#pragma unroll
  for (int i = 0; i < 4; ++i) acc[i] = make_float4(0.f, 0.f, 0.f, 0.f);

  for (int k0 = 0; k0 < 256; k0 += 16) {
    float4 wv = *(const float4*)(A + (o0 + wr) * 256 + k0 + wc);
    float4 xv = *(const float4*)(B + (k0 + xr) * 4096 + n0 + xc);
    Wt[wr][wc + 0] = wv.x; Wt[wr][wc + 1] = wv.y;
    Wt[wr][wc + 2] = wv.z; Wt[wr][wc + 3] = wv.w;
    *(float4*)&Xt[xr][xc] = xv;
    __syncthreads();
#pragma unroll
    for (int kk = 0; kk < 16; ++kk) {
      float4 b = *(const float4*)&Xt[kk][tx << 2];
#pragma unroll
      for (int i = 0; i < 4; ++i) {
        float a = Wt[(ty << 2) + i][kk];
        acc[i].x += a * b.x; acc[i].y += a * b.y;
        acc[i].z += a * b.z; acc[i].w += a * b.w;
      }
    }
    __syncthreads();
  }

  if (SCATTER) {
#pragma unroll
    for (int i = 0; i < 4; ++i) {
      int o = o0 + (ty << 2) + i;
      int which = o >> 8, rem = o & 255;
      int h = rem >> 5, d = rem & 31;
      int n = n0 + (tx << 2);
      if (which == 1) {
        // KT[h][d][n..n+3]: contiguous float4
        *(float4*)(C1 + h * (HD * NTOK) + d * NTOK + n) = acc[i];
      } else if (which == 2) {
        // V16[h][n][d]: fp16, scattered 2B stores
        __fp16* vh = (__fp16*)C2;
        int base = h * (NTOK * HD) + d;
        vh[base + (n + 0) * HD] = (__fp16)acc[i].x;
        vh[base + (n + 1) * HD] = (__fp16)acc[i].y;
        vh[base + (n + 2) * HD] = (__fp16)acc[i].z;
        vh[base + (n + 3) * HD] = (__fp16)acc[i].w;
      } else {
        // Q[h][n][d]: scattered fp32 (norm'd per row later)
        int base = h * (NTOK * HD) + d;
        C0[base + (n + 0) * HD] = acc[i].x;
        C0[base + (n + 1) * HD] = acc[i].y;
        C0[base + (n + 2) * HD] = acc[i].z;
        C0[base + (n + 3) * HD] = acc[i].w;
      }
    }
  } else {
#pragma unroll
    for (int i = 0; i < 4; ++i) {
      int o = o0 + (ty << 2) + i;
      *(float4*)(C0 + o * 4096 + n0 + (tx << 2)) = acc[i];
    }
  }
}

// ---- kernel 2a: l2norm Q rows [h][n][32], folds SCALE ---------------------

__global__ __launch_bounds__(256) void l2norm_q(float* __restrict__ Q) {
  const int tid = threadIdx.x;
  const int p = blockIdx.x * 8 + (tid >> 5);  // (head*4096+n) row index
  const int d = tid & 31;
  const int idx = p * HD + d;
  float v = Q[idx];
  float ss = v * v;
#pragma unroll
  for (int m = 16; m >= 1; m >>= 1) ss += __shfl_xor(ss, m, 32);
  float nrm = sqrtf(ss);
  Q[idx] = v * SCALE / fmaxf(nrm, 1e-12f);
}

// ---- kernel 2b: l2norm KT columns + fp16 d-pair pack (in place) -----------
// Reads KT[h][d][n] (fp32, all 32 d at fixed n), normalizes, writes packed
// fp16 pairs K16[h][d2][n] = (k[2d2],k[2d2+1]) over KT's first 16 rows.
// Aliasing is column-local (thread reads its column fully before storing).

__global__ __launch_bounds__(256) void l2norm_kt_pack(float* __restrict__ KT) {
  const int n = blockIdx.x * 256 + threadIdx.x;
  float* P = KT + blockIdx.y * (HD * NTOK) + n;
  float v[HD];
  float ss = 0.f;
#pragma unroll
  for (int d = 0; d < HD; ++d) {
    v[d] = P[d * NTOK];          // coalesced across lanes
    ss += v[d] * v[d];
  }
  float inv = 1.f / fmaxf(sqrtf(ss), 1e-12f);
  unsigned* O = (unsigned*)P;    // in-place: rows 0..15 as pair words
#pragma unroll
  for (int d2 = 0; d2 < 16; ++d2) {
#if USE_DOT2
    O[d2 * NTOK] = asu32(
        __builtin_amdgcn_cvt_pkrtz(v[2 * d2] * inv, v[2 * d2 + 1] * inv));
#else
    f16x2 p; p[0] = (__fp16)(v[2 * d2] * inv); p[1] = (__fp16)(v[2 * d2 + 1] * inv);
    O[d2 * NTOK] = asu32(p);
#endif
  }
}

// ---- kernel 3: fused attention (4 rows per block, column-partitioned) -----
// phase1: stage 4 q rows (fp32) + pack fp16 q d-pairs into LDS (once).
// phase2: thread tid owns cols {g*1024 + tid*4 + t}; 16 d2-iters of
//         {4 coalesced b128 K-pair loads + 4 broadcast b32 q-pair reads +
//          64 v_dot2_f32_f16} -> kr[4][16] fp32.  (R26 verbatim)
// phase3: hybrid selection (R19 window). Counts readfirstlane'd.
// phase4: fp16 weights wts2[m][4] (8B/col) -> two b128 stores per 4 cols;
//         exact integer denominators, block-reduced.
// phase5: PV via v_pk_fma_f16 over d-pairs: per m = 1 ds_read_b64 +
//         1 global b64 (V16) + 4 v_perm dup + 8 pk_fma. fp16 accumulate,
//         fp32 cross-lane reduce.

__global__ __launch_bounds__(256, 5) void attn_kernel(
    const float* __restrict__ Q, const float* __restrict__ KT,
    const __fp16* __restrict__ V16, float* __restrict__ AO) {
  __shared__ __align__(16) __fp16 wts2[NTOK][4];          // 32 KB, [m][row]
  __shared__ float qs[128];
  __shared__ unsigned qs2u[4][16];                        // fp16 q d-pairs
  __shared__ float pvred[4 * 8 * 4 * 4];                  // 2 KB
  __shared__ unsigned ired[2][4][2];                      // bisection dbuf
  __shared__ unsigned dred[4][4];                         // denom partials

  const int tid = threadIdx.x;
  const int wv = tid >> 6, lane = tid & 63;
  const int head = blockIdx.x & 7;          // head == blockIdx%8 -> XCD-pinned
  const int n0 = (blockIdx.x >> 3) << 2;

  const float* Qh = Q + head * (NTOK * HD);
  const float* KTh = KT + head * (HD * NTOK);
  const __fp16* Vh = V16 + head * (NTOK * HD);

  // phase 1: stage the block's 4 q rows (already *SCALE from l2norm_q),
  // then pack fp16 d-pairs (once per block).
  if (tid < 128) qs[tid] = Qh[n0 * HD + tid];
  __syncthreads();
  if (tid < 64) {
    const int r = tid >> 4, d2 = tid & 15;
#if USE_DOT2
    qs2u[r][d2] = asu32(__builtin_amdgcn_cvt_pkrtz(
        qs[r * HD + (d2 << 1)], qs[r * HD + (d2 << 1) + 1]));
#else
    f16x2 p; p[0] = (__fp16)qs[r * HD + (d2 << 1)];
    p[1] = (__fp16)qs[r * HD + (d2 << 1) + 1];
    qs2u[r][d2] = asu32(p);
#endif
  }
  __syncthreads();

  // phase 2: kr[r][g*4+t] = score(row r, col g*1024 + tid*4 + t) via dot2
  // over d-pairs. Each K pair-word read by exactly ONE thread of the block.
  float kr[4][16];
#pragma unroll
  for (int r = 0; r < 4; ++r)
#pragma unroll
    for (int j = 0; j < 16; ++j) kr[r][j] = 0.f;

  const int cb = tid << 2;
  const unsigned* k16 = (const unsigned*)KTh + cb;   // [16][NTOK] pair words
#pragma unroll 1
  for (int d2 = 0; d2 < 16; ++d2) {
    const unsigned* kp = k16 + d2 * NTOK;
    const uint4 kv0 = *(const uint4*)(kp);
    const uint4 kv1 = *(const uint4*)(kp + 1024);
    const uint4 kv2 = *(const uint4*)(kp + 2048);
    const uint4 kv3 = *(const uint4*)(kp + 3072);
    const unsigned qu0 = qs2u[0][d2], qu1 = qs2u[1][d2];
    const unsigned qu2 = qs2u[2][d2], qu3 = qs2u[3][d2];
#if USE_DOT2
    const f16x2 q0 = asv2h(qu0), q1 = asv2h(qu1);
    const f16x2 q2 = asv2h(qu2), q3 = asv2h(qu3);
#define DOT16(r, qv)                                                         \
    kr[r][0]  = __builtin_amdgcn_fdot2(qv, asv2h(kv0.x), kr[r][0],  false);  \
    kr[r][1]  = __builtin_amdgcn_fdot2(qv, asv2h(kv0.y), kr[r][1],  false);  \
    kr[r][2]  = __builtin_amdgcn_fdot2(qv, asv2h(kv0.z), kr[r][2],  false);  \
    kr[r][3]  = __builtin_amdgcn_fdot2(qv, asv2h(kv0.w), kr[r][3],  false);  \
    kr[r][4]  = __builtin_amdgcn_fdot2(qv, asv2h(kv1.x), kr[r][4],  false);  \
    kr[r][5]  = __builtin_amdgcn_fdot2(qv, asv2h(kv1.y), kr[r][5],  false);  \
    kr[r][6]  = __builtin_amdgcn_fdot2(qv, asv2h(kv1.z), kr[r][6],  false);  \
    kr[r][7]  = __builtin_amdgcn_fdot2(qv, asv2h(kv1.w), kr[r][7],  false);  \
    kr[r][8]  = __builtin_amdgcn_fdot2(qv, asv2h(kv2.x), kr[r][8],  false);  \
    kr[r][9]  = __builtin_amdgcn_fdot2(qv, asv2h(kv2.y), kr[r][9],  false);  \
    kr[r][10] = __builtin_amdgcn_fdot2(qv, asv2h(kv2.z), kr[r][10], false);  \
    kr[r][11] = __builtin_amdgcn_fdot2(qv, asv2h(kv2.w), kr[r][11], false);  \
    kr[r][12] = __builtin_amdgcn_fdot2(qv, asv2h(kv3.x), kr[r][12], false);  \
    kr[r][13] = __builtin_amdgcn_fdot2(qv, asv2h(kv3.y), kr[r][13], false);  \
    kr[r][14] = __builtin_amdgcn_fdot2(qv, asv2h(kv3.z), kr[r][14], false);  \
    kr[r][15] = __builtin_amdgcn_fdot2(qv, asv2h(kv3.w), kr[r][15], false);
    DOT16(0, q0) DOT16(1, q1) DOT16(2, q2) DOT16(3, q3)
#undef DOT16
#else
#define DOTF(r, qu)                                                          \
    {                                                                        \
      const f16x2 qq = asv2h(qu);                                            \
      const float qa = (float)qq[0], qb = (float)qq[1];                      \
      const unsigned kk[16] = {kv0.x, kv0.y, kv0.z, kv0.w, kv1.x, kv1.y,     \
                               kv1.z, kv1.w, kv2.x, kv2.y, kv2.z, kv2.w,     \
                               kv3.x, kv3.y, kv3.z, kv3.w};                  \
      _Pragma("unroll")                                                      \
      for (int j = 0; j < 16; ++j) {                                         \
        const f16x2 kh = asv2h(kk[j]);                                       \
        kr[r][j] += qa * (float)kh[0] + qb * (float)kh[1];                   \
      }                                                                      \
    }
    DOTF(0, qu0) DOTF(1, qu1) DOTF(2, qu2) DOTF(3, qu3)
#undef DOTF
#endif
  }

  // phase 3: hybrid selection per row (R19 schedule). Bracket invariant
  // (key space): count(klo) >= KSEL, answer in [klo, khi]. RF probe while
  // it<8 && width>65536; ulp midpoint after. Exit on count==KSEL (kept set
  // == top-k of the COMPUTED scores; ties make the count skip KSEL so
  // ==KSEL is tie-free) or klo==khi (exact kth key).
  // |scores| <= 0.1768 < 0.25, so anchors (-0.25 -> 4096, +0.25 -> 0).
  // State block-uniform; counts readfirstlane'd -> SGPR/SALU resident.
  unsigned klo0 = 0x417FFFFFu, khi0 = 0xBE800000u;  // fkey(-.25), fkey(.25)
  unsigned klo1 = 0x417FFFFFu, khi1 = 0xBE800000u;
  unsigned klo2 = 0x417FFFFFu, khi2 = 0xBE800000u;
  unsigned klo3 = 0x417FFFFFu, khi3 = 0xBE800000u;
  float xlo0 = -0.25f, xhi0 = 0.25f, xlo1 = -0.25f, xhi1 = 0.25f;
  float xlo2 = -0.25f, xhi2 = 0.25f, xlo3 = -0.25f, xhi3 = 0.25f;
  int clo0 = NTOK, chi0 = 0, clo1 = NTOK, chi1 = 0;
  int clo2 = NTOK, chi2 = 0, clo3 = NTOK, chi3 = 0;
  bool dn0 = false, dn1 = false, dn2 = false, dn3 = false;
  int slot = 0;
#pragma unroll 1
  for (int it = 0; it < 40; ++it) {
    unsigned m0 = dn0 ? klo0
        : ((it < 8 && (khi0 - klo0) > 65536u)
               ? rfl_u(probe_rf(klo0, khi0, xlo0, xhi0, clo0, chi0))
               : klo0 + ((khi0 - klo0 + 1u) >> 1));
    unsigned m1 = dn1 ? klo1
        : ((it < 8 && (khi1 - klo1) > 65536u)
               ? rfl_u(probe_rf(klo1, khi1, xlo1, xhi1, clo1, chi1))
               : klo1 + ((khi1 - klo1 + 1u) >> 1));
    unsigned m2 = dn2 ? klo2
        : ((it < 8 && (khi2 - klo2) > 65536u)
               ? rfl_u(probe_rf(klo2, khi2, xlo2, xhi2, clo2, chi2))
               : klo2 + ((khi2 - klo2 + 1u) >> 1));
    unsigned m3 = dn3 ? klo3
        : ((it < 8 && (khi3 - klo3) > 65536u)
               ? rfl_u(probe_rf(klo3, khi3, xlo3, xhi3, clo3, chi3))
               : klo3 + ((khi3 - klo3 + 1u) >> 1));
    unsigned c0 = 0, c1 = 0, c2 = 0, c3 = 0;
    if (!dn0) {
      const float f0 = unfkey(m0);
#pragma unroll
      for (int j = 0; j < 16; ++j) c0 += __popcll(__ballot(kr[0][j] >= f0));
    }
    if (!dn1) {
      const float f1 = unfkey(m1);
#pragma unroll
      for (int j = 0; j < 16; ++j) c1 += __popcll(__ballot(kr[1][j] >= f1));
    }
    if (!dn2) {
      const float f2 = unfkey(m2);
#pragma unroll
      for (int j = 0; j < 16; ++j) c2 += __popcll(__ballot(kr[2][j] >= f2));
    }
    if (!dn3) {
      const float f3 = unfkey(m3);
#pragma unroll
      for (int j = 0; j < 16; ++j) c3 += __popcll(__ballot(kr[3][j] >= f3));
    }
    if (lane == 0) {
      ired[slot][wv][0] = c0 | (c1 << 16);
      ired[slot][wv][1] = c2 | (c3 << 16);
    }
    __syncthreads();
    unsigned a01 = rfl_u(ired[slot][0][0] + ired[slot][1][0] +
                         ired[slot][2][0] + ired[slot][3][0]);
    unsigned a23 = rfl_u(ired[slot][0][1] + ired[slot][1][1] +
                         ired[slot][2][1] + ired[slot][3][1]);
    slot ^= 1;
    int C0 = (int)(a01 & 0xFFFFu), C1 = (int)(a01 >> 16);
    int C2 = (int)(a23 & 0xFFFFu), C3 = (int)(a23 >> 16);
#define BUPD(C, klo, khi, xlo, xhi, clo, chi, dn, mk)                        \
    if (!dn) {                                                               \
      if (C == KSEL) { klo = mk; dn = true; }                                \
      else if (C > KSEL) { klo = mk; xlo = unfkey(mk); clo = C; }            \
      else { khi = mk - 1u; xhi = unfkey(mk); chi = C; }                     \
      if (klo >= khi) dn = true;                                             \
    }
    BUPD(C0, klo0, khi0, xlo0, xhi0, clo0, chi0, dn0, m0)
    BUPD(C1, klo1, khi1, xlo1, xhi1, clo1, chi1, dn1, m1)
    BUPD(C2, klo2, khi2, xlo2, xhi2, clo2, chi2, dn2, m2)
    BUPD(C3, klo3, khi3, xlo3, xhi3, clo3, chi3, dn3, m3)
#undef BUPD
    if (dn0 && dn1 && dn2 && dn3) break;   // uniform across block
  }
  const float tf0 = unfkey(klo0), tf1 = unfkey(klo1);
  const float tf2 = unfkey(klo2), tf3 = unfkey(klo3);

  // phase 4: fp16 weights wts2[m][4] (8B per column). u = rint(exp(s) *
  // 255/e^smax) in [179,255] kept, 0 masked; integers exact in fp16.
  // Thread's 4 consecutive cols = 32B contiguous -> two b128 stores.
  unsigned id0 = 0, id1 = 0, id2 = 0, id3 = 0;
#pragma unroll
  for (int g = 0; g < 4; ++g) {
    unsigned pk[8];
#pragma unroll
    for (int t = 0; t < 4; ++t) {
      const int j = (g << 2) + t;
      float s0 = kr[0][j], s1 = kr[1][j], s2 = kr[2][j], s3 = kr[3][j];
      float u0 = (s0 >= tf0) ? rintf(exp2f(__builtin_fmaf(s0, 1.44269504f, LOG2C))) : 0.f;
      float u1 = (s1 >= tf1) ? rintf(exp2f(__builtin_fmaf(s1, 1.44269504f, LOG2C))) : 0.f;
      float u2 = (s2 >= tf2) ? rintf(exp2f(__builtin_fmaf(s2, 1.44269504f, LOG2C))) : 0.f;
      float u3 = (s3 >= tf3) ? rintf(exp2f(__builtin_fmaf(s3, 1.44269504f, LOG2C))) : 0.f;
      id0 += (unsigned)u0; id1 += (unsigned)u1;
      id2 += (unsigned)u2; id3 += (unsigned)u3;
#if USE_DOT2
      pk[(t << 1) + 0] = asu32(__builtin_amdgcn_cvt_pkrtz(u0, u1));
      pk[(t << 1) + 1] = asu32(__builtin_amdgcn_cvt_pkrtz(u2, u3));
#else
      { f16x2 a; a[0] = (__fp16)u0; a[1] = (__fp16)u1; pk[(t << 1) + 0] = asu32(a); }
      { f16x2 b; b[0] = (__fp16)u2; b[1] = (__fp16)u3; pk[(t << 1) + 1] = asu32(b); }
#endif
    }
    const int col = (g << 10) + cb;            // addr = col*8, 16B-aligned
    *(uint4*)&wts2[col][0]     = make_uint4(pk[0], pk[1], pk[2], pk[3]);
    *(uint4*)&wts2[col + 2][0] = make_uint4(pk[4], pk[5], pk[6], pk[7]);
  }
  // exact integer denominators: wave-reduce then cross-wave sum
#pragma unroll
  for (int s = 1; s < 64; s <<= 1) {
    id0 += __shfl_xor(id0, s); id1 += __shfl_xor(id1, s);
    id2 += __shfl_xor(id2, s); id3 += __shfl_xor(id3, s);
  }
  if (lane == 0) *(uint4*)&dred[wv][0] = make_uint4(id0, id1, id2, id3);
  __syncthreads();  // wts2 + dred visible to all
  const float dnm0 = (float)(dred[0][0] + dred[1][0] + dred[2][0] + dred[3][0]);
  const float dnm1 = (float)(dred[0][1] + dred[1][1] + dred[2][1] + dred[3][1]);
  const float dnm2 = (float)(dred[0][2] + dred[1][2] + dred[2][2] + dred[3][2]);
  const float dnm3 = (float)(dred[0][3] + dred[1][3] + dred[2][3] + dred[3][3]);

  // phase 5: PV via pk_fma over d-pairs, all-fp16 operands (convert-once).
  // wave wv covers m in [wv*1024, +1024); lane-group mg owns m stride 8,
  // slot5 owns d-quad. Per m: 1 ds_read_b64 (w0..w3, broadcast over 8
  // lanes, conflict-free) + 1 global b64 (V16 4d slice, coalesced 64B per
  // mg-group) + 4 dup + 8 v_pk_fma_f16.
  const int slot5 = lane & 7, mg = lane >> 3;
  const int mbase = wv << 10;
  f16x2 av2[4][2];
#pragma unroll
  for (int r = 0; r < 4; ++r)
#pragma unroll
    for (int c = 0; c < 2; ++c) { av2[r][c][0] = (__fp16)0.f; av2[r][c][1] = (__fp16)0.f; }

#pragma unroll 4
  for (int ii = 0; ii < 128; ++ii) {
    const int m = mbase + (ii << 3) + mg;
    const uint2 wq = *(const uint2*)&wts2[m][0];       // (w0,w1),(w2,w3)
    const uint2 vv = *(const uint2*)(Vh + m * HD + (slot5 << 2));
    const f16x2 va = asv2h(vv.x), vb = asv2h(vv.y);
    const f16x2 w00 = asv2h(dup_lo16(wq.x));
    const f16x2 w11 = asv2h(dup_hi16(wq.x));
    const f16x2 w22 = asv2h(dup_lo16(wq.y));
    const f16x2 w33 = asv2h(dup_hi16(wq.y));
    av2[0][0] += w00 * va; av2[0][1] += w00 * vb;
    av2[1][0] += w11 * va; av2[1][1] += w11 * vb;
    av2[2][0] += w22 * va; av2[2][1] += w22 * vb;
    av2[3][0] += w33 * va; av2[3][1] += w33 * vb;
  }
  // convert to fp32 and reduce over mg (lane bits 3..5)
  float av[4][4];
#pragma unroll
  for (int r = 0; r < 4; ++r) {
    av[r][0] = (float)av2[r][0][0]; av[r][1] = (float)av2[r][0][1];
    av[r][2] = (float)av2[r][1][0]; av[r][3] = (float)av2[r][1][1];
  }
#pragma unroll
  for (int r = 0; r < 4; ++r)
#pragma unroll
    for (int c = 0; c < 4; ++c) {
      float x = av[r][c];
      x += __shfl_xor(x, 8); x += __shfl_xor(x, 16); x += __shfl_xor(x, 32);
      av[r][c] = x;
    }
  if (mg == 0) {
#pragma unroll
    for (int r = 0; r < 4; ++r)
#pragma unroll
      for (int c = 0; c < 4; ++c)
        pvred[(((wv << 3) + slot5) * 4 + r) * 4 + c] = av[r][c];
  }
  __syncthreads();

  if (tid < 128) {
    const int r = tid >> 5, d = tid & 31;
    const int sl = d >> 2, c = d & 3;
    float val = 0.f;
#pragma unroll
    for (int w = 0; w < 4; ++w) val += pvred[(((w << 3) + sl) * 4 + r) * 4 + c];
    float dn = (r == 0) ? dnm0 : (r == 1) ? dnm1 : (r == 2) ? dnm2 : dnm3;
    val /= dn;
    AO[(head * HD + d) * NTOK + n0 + r] = val;  // [C][N] for proj GEMM
  }
}

// ---- kernel 5: GroupNorm stats (32 groups of 8 ch x 4096 = 32768 vals) ----

__global__ __launch_bounds__(256) void gn_stats(const float* __restrict__ O,
                                                float* __restrict__ ST) {
  const int g = blockIdx.x, tid = threadIdx.x;
  const float4* p4 = (const float4*)(O + g * 32768);
  float s = 0.f, ss = 0.f;
  for (int i = tid; i < 8192; i += 256) {
    float4 v = p4[i];
    s += (v.x + v.y) + (v.z + v.w);
    ss += (v.x * v.x + v.y * v.y) + (v.z * v.z + v.w * v.w);
  }
#pragma unroll
  for (int m = 1; m < 64; m <<= 1) {
    s += __shfl_xor(s, m);
    ss += __shfl_xor(ss, m);
  }
  __shared__ float rs[4], rss[4];
  if ((tid & 63) == 0) { rs[tid >> 6] = s; rss[tid >> 6] = ss; }
  __syncthreads();
  if (tid == 0) {
    float S = rs[0] + rs[1] + rs[2] + rs[3];
    float SS = rss[0] + rss[1] + rss[2] + rss[3];
    float mean = S * (1.f / 32768.f);
    float var = SS * (1.f / 32768.f) - mean * mean;
    ST[g * 2] = mean;
    ST[g * 2 + 1] = rsqrtf(var + 1e-6f);
  }
}

// ---- kernel 6: GroupNorm apply (in place on d_out) ------------------------
// Indexes FLOAT4s: total 1048576/4 = 262144 -> grid 1024 x 256.

__global__ __launch_bounds__(256) void gn_apply(float* __restrict__ O,
                                                const float* __restrict__ ST,
                                                const float* __restrict__ gamma,
                                                const float* __restrict__ beta) {
  const int i4 = blockIdx.x * 256 + threadIdx.x;  // float4 index
  const int c = i4 >> 10, g = c >> 3;
  const float a = ST[g * 2 + 1] * gamma[c];
  const float b = beta[c] - ST[g * 2] * a;
  float4 v = *(float4*)(O + (i4 << 2));
  v.x = v.x * a + b; v.y = v.y * a + b; v.z = v.z * a + b; v.w = v.w * a + b;
  *(float4*)(O + (i4 << 2)) = v;
}

// ---- launch ---------------------------------------------------------------

extern "C" void kernel_launch(void* const* d_in, const int* in_sizes, int n_in,
                              void* d_out, int out_size, void* d_ws,
                              size_t ws_size, hipStream_t stream) {
  const float* x = (const float*)d_in[0];       // [256][4096]
  const float* w_qkv = (const float*)d_in[1];   // [768][256]
  const float* w_proj = (const float*)d_in[2];  // [256][256]
  const float* gamma = (const float*)d_in[3];   // [256]
  const float* beta = (const float*)d_in[4];    // [256]
  float* out = (float*)d_out;                   // [256][4096]

  float* Q = (float*)d_ws;          // [8][4096][32] fp32
  float* KT = Q + 1048576;          // [8][32][4096] fp32 -> fp16 pairs in place
  float* V16r = KT + 1048576;       // [8][4096][32] FP16 (2MB of the 4MB slot)
  float* AO = V16r + 1048576;       // [256][4096] fp32
  float* ST = AO + 1048576;         // [32][2]

  gemm_k256<true><<<dim3(64, 12), 256, 0, stream>>>(w_qkv, x, Q, KT, V16r);
  l2norm_q<<<4096, 256, 0, stream>>>(Q);
  l2norm_kt_pack<<<dim3(16, 8), 256, 0, stream>>>(KT);
  attn_kernel<<<8192, 256, 0, stream>>>(Q, KT, (const __fp16*)V16r, AO);
  gemm_k256<false><<<dim3(64, 4), 256, 0, stream>>>(w_proj, AO, out, nullptr, nullptr);
  gn_stats<<<32, 256, 0, stream>>>(out, ST);
  gn_apply<<<1024, 256, 0, stream>>>(out, ST, gamma, beta);
}

// Round 17
// 425.749 us; speedup vs baseline: 1.0859x; 1.0435x over previous
//
#include <hip/hip_runtime.h>

// ---------------------------------------------------------------------------
// LowFreqSparseAttention: qkv 1x1conv -> l2norm(q,k) -> S=QK^T*scale ->
// top-k(k=N/2) mask -> softmax -> PV -> proj 1x1conv -> GroupNorm(32 groups).
// B=1, C=256, H=W=64 -> N=4096, 8 heads, hd=32, k_sel=2048.
//
// R30 = R29 (362us attn, best) + two cuts:
//  1. phase5 weight broadcast via __builtin_shufflevector (NOT amdgcn_perm)
//     -> backend folds the (w,w) splat into v_pk_fma_f16 op_sel, deleting
//     4 dup insts/m (-512/thread ~ 10% of remaining issue). V loaded as one
//     f16x4 b64 with free subvector extracts.
//  2. l2norm_q FUSED into attn phase 1 (each Q row read by exactly one
//     block; 32-lane shfl_xor reduce in the staging path). One fewer
//     4096-block kernel (~8us).
// R29 post-mortem: convert-once pk_fma paid (371->362, 3rd confirmation of
// the rule); shortfall vs prediction traced to the explicit perm dups
// (unfoldable) and occ 42%. Counters clean (WRITE 4MB, FETCH 4.2MB).
// Predict: attn ~345-355 (flat => op_sel didn't fold -> declare floor),
// total ~425-435, absmax 0.047 unchanged.
// ---------------------------------------------------------------------------

#define NTOK 4096
#define HD 32
#define NHEADS 8
#define KSEL 2048
#define SCALE 0.17677669529663689f   // 32^-0.5  (folded into fused q-norm)
#define LOG2C 7.73937f               // log2(255 / e^0.1767767)

typedef __fp16 f16x2 __attribute__((ext_vector_type(2)));
typedef __fp16 f16x4v __attribute__((ext_vector_type(4)));

#define USE_DOT2 (__has_builtin(__builtin_amdgcn_fdot2) && \
                  __has_builtin(__builtin_amdgcn_cvt_pkrtz))

// ---- helpers --------------------------------------------------------------

__device__ __forceinline__ unsigned fkey(float f) {
  unsigned b = __float_as_uint(f);
  return (b & 0x80000000u) ? ~b : (b | 0x80000000u);
}
__device__ __forceinline__ float unfkey(unsigned k) {
  unsigned b = (k & 0x80000000u) ? (k ^ 0x80000000u) : ~k;
  return __uint_as_float(b);
}
__device__ __forceinline__ unsigned rfl_u(unsigned x) {  // force SGPR
  return __builtin_amdgcn_readfirstlane(x);
}
__device__ __forceinline__ f16x2 asv2h(unsigned u) {
  union { unsigned u; f16x2 h; } c; c.u = u; return c.h;
}
__device__ __forceinline__ unsigned asu32(f16x2 h) {
  union { f16x2 h; unsigned u; } c; c.h = h; return c.u;
}
// regula-falsi probe in key space, clamped to (klo, khi]
__device__ __forceinline__ unsigned probe_rf(unsigned klo, unsigned khi,
                                             float xlo, float xhi,
                                             int clo, int chi) {
  float t = xlo + (xhi - xlo) * ((float)(clo - KSEL) / (float)(clo - chi));
  unsigned k = fkey(t);
  if (k <= klo) k = klo + 1u;
  if (k > khi) k = khi;
  return k;
}

// ---- kernel 1/4: GEMM  C[M][4096] = A[M][256] * B[256][4096] --------------
// SCATTER: M=768 -> Q [h][n][d] fp32, KT [h][d][n] fp32 (transposed),
//          V16 [h][n][d] FP16 (scattered 2B stores).
// else:    M=256 -> plain row-major C0.

template <bool SCATTER>
__global__ __launch_bounds__(256) void gemm_k256(
    const float* __restrict__ A, const float* __restrict__ B,
    float* __restrict__ C0, float* __restrict__ C1, float* __restrict__ C2) {
  __shared__ float Wt[64][17];   // +1 pad: avoid 16-way bank conflict
  __shared__ float Xt[16][64];

  const int tid = threadIdx.x;
  const int tx = tid & 15, ty = tid >> 4;
  const int o0 = blockIdx.y * 64, n0 = blockIdx.x * 64;

  const int wr = tid >> 2, wc = (tid & 3) << 2;   // W-tile 64x16 loader
  const int xr = tid >> 4, xc = (tid & 15) << 2;  // X-tile 16x64 loader

  float4 acc[4];
#pragma unroll
  for (int i = 0; i < 4; ++i) acc[i] = make_float4(0.f, 0.f, 0.f, 0.f);

  for (int k0 = 0; k0 < 256; k0 += 16) {
    float4 wv = *(const float4*)(A + (o0 + wr) * 256 + k0 + wc);
    float4 xv = *(const float4*)(B + (k0 + xr) * 4096 + n0 + xc);
    Wt[wr][wc + 0] = wv.x; Wt[wr][wc + 1] = wv.y;
    Wt[wr][wc + 2] = wv.z; Wt[wr][wc + 3] = wv.w;
    *(float4*)&Xt[xr][xc] = xv;
    __syncthreads();
#pragma unroll
    for (int kk = 0; kk < 16; ++kk) {
      float4 b = *(const float4*)&Xt[kk][tx << 2];
#pragma unroll
      for (int i = 0; i < 4; ++i) {
        float a = Wt[(ty << 2) + i][kk];
        acc[i].x += a * b.x; acc[i].y += a * b.y;
        acc[i].z += a * b.z; acc[i].w += a * b.w;
      }
    }
    __syncthreads();
  }

  if (SCATTER) {
#pragma unroll
    for (int i = 0; i < 4; ++i) {
      int o = o0 + (ty << 2) + i;
      int which = o >> 8, rem = o & 255;
      int h = rem >> 5, d = rem & 31;
      int n = n0 + (tx << 2);
      if (which == 1) {
        // KT[h][d][n..n+3]: contiguous float4
        *(float4*)(C1 + h * (HD * NTOK) + d * NTOK + n) = acc[i];
      } else if (which == 2) {
        // V16[h][n][d]: fp16, scattered 2B stores
        __fp16* vh = (__fp16*)C2;
        int base = h * (NTOK * HD) + d;
        vh[base + (n + 0) * HD] = (__fp16)acc[i].x;
        vh[base + (n + 1) * HD] = (__fp16)acc[i].y;
        vh[base + (n + 2) * HD] = (__fp16)acc[i].z;
        vh[base + (n + 3) * HD] = (__fp16)acc[i].w;
      } else {
        // Q[h][n][d]: scattered fp32 (normalized in attn phase 1)
        int base = h * (NTOK * HD) + d;
        C0[base + (n + 0) * HD] = acc[i].x;
        C0[base + (n + 1) * HD] = acc[i].y;
        C0[base + (n + 2) * HD] = acc[i].z;
        C0[base + (n + 3) * HD] = acc[i].w;
      }
    }
  } else {
#pragma unroll
    for (int i = 0; i < 4; ++i) {
      int o = o0 + (ty << 2) + i;
      *(float4*)(C0 + o * 4096 + n0 + (tx << 2)) = acc[i];
    }
  }
}

// ---- kernel 2: l2norm KT columns + fp16 d-pair pack (in place) ------------
// Reads KT[h][d][n] (fp32, all 32 d at fixed n), normalizes, writes packed
// fp16 pairs K16[h][d2][n] = (k[2d2],k[2d2+1]) over KT's first 16 rows.
// Aliasing is column-local (thread reads its column fully before storing).

__global__ __launch_bounds__(256) void l2norm_kt_pack(float* __restrict__ KT) {
  const int n = blockIdx.x * 256 + threadIdx.x;
  float* P = KT + blockIdx.y * (HD * NTOK) + n;
  float v[HD];
  float ss = 0.f;
#pragma unroll
  for (int d = 0; d < HD; ++d) {
    v[d] = P[d * NTOK];          // coalesced across lanes
    ss += v[d] * v[d];
  }
  float inv = 1.f / fmaxf(sqrtf(ss), 1e-12f);
  unsigned* O = (unsigned*)P;    // in-place: rows 0..15 as pair words
#pragma unroll
  for (int d2 = 0; d2 < 16; ++d2) {
#if USE_DOT2
    O[d2 * NTOK] = asu32(
        __builtin_amdgcn_cvt_pkrtz(v[2 * d2] * inv, v[2 * d2 + 1] * inv));
#else
    f16x2 p; p[0] = (__fp16)(v[2 * d2] * inv); p[1] = (__fp16)(v[2 * d2 + 1] * inv);
    O[d2 * NTOK] = asu32(p);
#endif
  }
}

// ---- kernel 3: fused attention (4 rows per block, column-partitioned) -----
// phase1: stage 4 q rows with FUSED l2norm (32-lane shfl reduce, *SCALE),
//         then pack fp16 q d-pairs into LDS (once).
// phase2: thread tid owns cols {g*1024 + tid*4 + t}; 16 d2-iters of
//         {4 coalesced b128 K-pair loads + 4 broadcast b32 q-pair reads +
//          64 v_dot2_f32_f16} -> kr[4][16] fp32.
// phase3: hybrid selection (R19 window). Counts readfirstlane'd.
// phase4: fp16 weights wts2[m][4] (8B/col) -> two b128 stores per 4 cols;
//         exact integer denominators, block-reduced.
// phase5: PV via v_pk_fma_f16 over d-pairs, weight splats expressed as
//         shufflevector -> op_sel folding (no dup insts). fp16 accumulate,
//         fp32 cross-lane reduce.

__global__ __launch_bounds__(256, 5) void attn_kernel(
    const float* __restrict__ Q, const float* __restrict__ KT,
    const __fp16* __restrict__ V16, float* __restrict__ AO) {
  __shared__ __align__(16) __fp16 wts2[NTOK][4];          // 32 KB, [m][row]
  __shared__ float qs[128];
  __shared__ unsigned qs2u[4][16];                        // fp16 q d-pairs
  __shared__ float pvred[4 * 8 * 4 * 4];                  // 2 KB
  __shared__ unsigned ired[2][4][2];                      // bisection dbuf
  __shared__ unsigned dred[4][4];                         // denom partials

  const int tid = threadIdx.x;
  const int wv = tid >> 6, lane = tid & 63;
  const int head = blockIdx.x & 7;          // head == blockIdx%8 -> XCD-pinned
  const int n0 = (blockIdx.x >> 3) << 2;

  const float* Qh = Q + head * (NTOK * HD);
  const float* KTh = KT + head * (HD * NTOK);
  const __fp16* Vh = V16 + head * (NTOK * HD);

  // phase 1: stage the block's 4 q rows with fused l2norm (each Q row is
  // read by exactly ONE block -> fusion is safe). Threads 0-127 span two
  // full waves; 32-lane xor-reduce = per-row sum of squares. Then pack
  // fp16 d-pairs (once per block).
  if (tid < 128) {
    float v = Qh[n0 * HD + tid];
    float ss = v * v;
#pragma unroll
    for (int m = 16; m >= 1; m >>= 1) ss += __shfl_xor(ss, m, 32);
    qs[tid] = v * SCALE / fmaxf(sqrtf(ss), 1e-12f);
  }
  __syncthreads();
  if (tid < 64) {
    const int r = tid >> 4, d2 = tid & 15;
#if USE_DOT2
    qs2u[r][d2] = asu32(__builtin_amdgcn_cvt_pkrtz(
        qs[r * HD + (d2 << 1)], qs[r * HD + (d2 << 1) + 1]));
#else
    f16x2 p; p[0] = (__fp16)qs[r * HD + (d2 << 1)];
    p[1] = (__fp16)qs[r * HD + (d2 << 1) + 1];
    qs2u[r][d2] = asu32(p);
#endif
  }
  __syncthreads();

  // phase 2: kr[r][g*4+t] = score(row r, col g*1024 + tid*4 + t) via dot2
  // over d-pairs. Each K pair-word read by exactly ONE thread of the block.
  float kr[4][16];
#pragma unroll
  for (int r = 0; r < 4; ++r)
#pragma unroll
    for (int j = 0; j < 16; ++j) kr[r][j] = 0.f;

  const int cb = tid << 2;
  const unsigned* k16 = (const unsigned*)KTh + cb;   // [16][NTOK] pair words
#pragma unroll 1
  for (int d2 = 0; d2 < 16; ++d2) {
    const unsigned* kp = k16 + d2 * NTOK;
    const uint4 kv0 = *(const uint4*)(kp);
    const uint4 kv1 = *(const uint4*)(kp + 1024);
    const uint4 kv2 = *(const uint4*)(kp + 2048);
    const uint4 kv3 = *(const uint4*)(kp + 3072);
    const unsigned qu0 = qs2u[0][d2], qu1 = qs2u[1][d2];
    const unsigned qu2 = qs2u[2][d2], qu3 = qs2u[3][d2];
#if USE_DOT2
    const f16x2 q0 = asv2h(qu0), q1 = asv2h(qu1);
    const f16x2 q2 = asv2h(qu2), q3 = asv2h(qu3);
#define DOT16(r, qv)                                                         \
    kr[r][0]  = __builtin_amdgcn_fdot2(qv, asv2h(kv0.x), kr[r][0],  false);  \
    kr[r][1]  = __builtin_amdgcn_fdot2(qv, asv2h(kv0.y), kr[r][1],  false);  \
    kr[r][2]  = __builtin_amdgcn_fdot2(qv, asv2h(kv0.z), kr[r][2],  false);  \
    kr[r][3]  = __builtin_amdgcn_fdot2(qv, asv2h(kv0.w), kr[r][3],  false);  \
    kr[r][4]  = __builtin_amdgcn_fdot2(qv, asv2h(kv1.x), kr[r][4],  false);  \
    kr[r][5]  = __builtin_amdgcn_fdot2(qv, asv2h(kv1.y), kr[r][5],  false);  \
    kr[r][6]  = __builtin_amdgcn_fdot2(qv, asv2h(kv1.z), kr[r][6],  false);  \
    kr[r][7]  = __builtin_amdgcn_fdot2(qv, asv2h(kv1.w), kr[r][7],  false);  \
    kr[r][8]  = __builtin_amdgcn_fdot2(qv, asv2h(kv2.x), kr[r][8],  false);  \
    kr[r][9]  = __builtin_amdgcn_fdot2(qv, asv2h(kv2.y), kr[r][9],  false);  \
    kr[r][10] = __builtin_amdgcn_fdot2(qv, asv2h(kv2.z), kr[r][10], false);  \
    kr[r][11] = __builtin_amdgcn_fdot2(qv, asv2h(kv2.w), kr[r][11], false);  \
    kr[r][12] = __builtin_amdgcn_fdot2(qv, asv2h(kv3.x), kr[r][12], false);  \
    kr[r][13] = __builtin_amdgcn_fdot2(qv, asv2h(kv3.y), kr[r][13], false);  \
    kr[r][14] = __builtin_amdgcn_fdot2(qv, asv2h(kv3.z), kr[r][14], false);  \
    kr[r][15] = __builtin_amdgcn_fdot2(qv, asv2h(kv3.w), kr[r][15], false);
    DOT16(0, q0) DOT16(1, q1) DOT16(2, q2) DOT16(3, q3)
#undef DOT16
#else
#define DOTF(r, qu)                                                          \
    {                                                                        \
      const f16x2 qq = asv2h(qu);                                            \
      const float qa = (float)qq[0], qb = (float)qq[1];                      \
      const unsigned kk[16] = {kv0.x, kv0.y, kv0.z, kv0.w, kv1.x, kv1.y,     \
                               kv1.z, kv1.w, kv2.x, kv2.y, kv2.z, kv2.w,     \
                               kv3.x, kv3.y, kv3.z, kv3.w};                  \
      _Pragma("unroll")                                                      \
      for (int j = 0; j < 16; ++j) {                                         \
        const f16x2 kh = asv2h(kk[j]);                                       \
        kr[r][j] += qa * (float)kh[0] + qb * (float)kh[1];                   \
      }                                                                      \
    }
    DOTF(0, qu0) DOTF(1, qu1) DOTF(2, qu2) DOTF(3, qu3)
#undef DOTF
#endif
  }

  // phase 3: hybrid selection per row (R19 schedule). Bracket invariant
  // (key space): count(klo) >= KSEL, answer in [klo, khi]. RF probe while
  // it<8 && width>65536; ulp midpoint after. Exit on count==KSEL (kept set
  // == top-k of the COMPUTED scores; ties make the count skip KSEL so
  // ==KSEL is tie-free) or klo==khi (exact kth key).
  // |scores| <= 0.1768 < 0.25, so anchors (-0.25 -> 4096, +0.25 -> 0).
  // State block-uniform; counts readfirstlane'd -> SGPR/SALU resident.
  unsigned klo0 = 0x417FFFFFu, khi0 = 0xBE800000u;  // fkey(-.25), fkey(.25)
  unsigned klo1 = 0x417FFFFFu, khi1 = 0xBE800000u;
  unsigned klo2 = 0x417FFFFFu, khi2 = 0xBE800000u;
  unsigned klo3 = 0x417FFFFFu, khi3 = 0xBE800000u;
  float xlo0 = -0.25f, xhi0 = 0.25f, xlo1 = -0.25f, xhi1 = 0.25f;
  float xlo2 = -0.25f, xhi2 = 0.25f, xlo3 = -0.25f, xhi3 = 0.25f;
  int clo0 = NTOK, chi0 = 0, clo1 = NTOK, chi1 = 0;
  int clo2 = NTOK, chi2 = 0, clo3 = NTOK, chi3 = 0;
  bool dn0 = false, dn1 = false, dn2 = false, dn3 = false;
  int slot = 0;
#pragma unroll 1
  for (int it = 0; it < 40; ++it) {
    unsigned m0 = dn0 ? klo0
        : ((it < 8 && (khi0 - klo0) > 65536u)
               ? rfl_u(probe_rf(klo0, khi0, xlo0, xhi0, clo0, chi0))
               : klo0 + ((khi0 - klo0 + 1u) >> 1));
    unsigned m1 = dn1 ? klo1
        : ((it < 8 && (khi1 - klo1) > 65536u)
               ? rfl_u(probe_rf(klo1, khi1, xlo1, xhi1, clo1, chi1))
               : klo1 + ((khi1 - klo1 + 1u) >> 1));
    unsigned m2 = dn2 ? klo2
        : ((it < 8 && (khi2 - klo2) > 65536u)
               ? rfl_u(probe_rf(klo2, khi2, xlo2, xhi2, clo2, chi2))
               : klo2 + ((khi2 - klo2 + 1u) >> 1));
    unsigned m3 = dn3 ? klo3
        : ((it < 8 && (khi3 - klo3) > 65536u)
               ? rfl_u(probe_rf(klo3, khi3, xlo3, xhi3, clo3, chi3))
               : klo3 + ((khi3 - klo3 + 1u) >> 1));
    unsigned c0 = 0, c1 = 0, c2 = 0, c3 = 0;
    if (!dn0) {
      const float f0 = unfkey(m0);
#pragma unroll
      for (int j = 0; j < 16; ++j) c0 += __popcll(__ballot(kr[0][j] >= f0));
    }
    if (!dn1) {
      const float f1 = unfkey(m1);
#pragma unroll
      for (int j = 0; j < 16; ++j) c1 += __popcll(__ballot(kr[1][j] >= f1));
    }
    if (!dn2) {
      const float f2 = unfkey(m2);
#pragma unroll
      for (int j = 0; j < 16; ++j) c2 += __popcll(__ballot(kr[2][j] >= f2));
    }
    if (!dn3) {
      const float f3 = unfkey(m3);
#pragma unroll
      for (int j = 0; j < 16; ++j) c3 += __popcll(__ballot(kr[3][j] >= f3));
    }
    if (lane == 0) {
      ired[slot][wv][0] = c0 | (c1 << 16);
      ired[slot][wv][1] = c2 | (c3 << 16);
    }
    __syncthreads();
    unsigned a01 = rfl_u(ired[slot][0][0] + ired[slot][1][0] +
                         ired[slot][2][0] + ired[slot][3][0]);
    unsigned a23 = rfl_u(ired[slot][0][1] + ired[slot][1][1] +
                         ired[slot][2][1] + ired[slot][3][1]);
    slot ^= 1;
    int C0 = (int)(a01 & 0xFFFFu), C1 = (int)(a01 >> 16);
    int C2 = (int)(a23 & 0xFFFFu), C3 = (int)(a23 >> 16);
#define BUPD(C, klo, khi, xlo, xhi, clo, chi, dn, mk)                        \
    if (!dn) {                                                               \
      if (C == KSEL) { klo = mk; dn = true; }                                \
      else if (C > KSEL) { klo = mk; xlo = unfkey(mk); clo = C; }            \
      else { khi = mk - 1u; xhi = unfkey(mk); chi = C; }                     \
      if (klo >= khi) dn = true;                                             \
    }
    BUPD(C0, klo0, khi0, xlo0, xhi0, clo0, chi0, dn0, m0)
    BUPD(C1, klo1, khi1, xlo1, xhi1, clo1, chi1, dn1, m1)
    BUPD(C2, klo2, khi2, xlo2, xhi2, clo2, chi2, dn2, m2)
    BUPD(C3, klo3, khi3, xlo3, xhi3, clo3, chi3, dn3, m3)
#undef BUPD
    if (dn0 && dn1 && dn2 && dn3) break;   // uniform across block
  }
  const float tf0 = unfkey(klo0), tf1 = unfkey(klo1);
  const float tf2 = unfkey(klo2), tf3 = unfkey(klo3);

  // phase 4: fp16 weights wts2[m][4] (8B per column). u = rint(exp(s) *
  // 255/e^smax) in [179,255] kept, 0 masked; integers exact in fp16.
  // Thread's 4 consecutive cols = 32B contiguous -> two b128 stores.
  unsigned id0 = 0, id1 = 0, id2 = 0, id3 = 0;
#pragma unroll
  for (int g = 0; g < 4; ++g) {
    unsigned pk[8];
#pragma unroll
    for (int t = 0; t < 4; ++t) {
      const int j = (g << 2) + t;
      float s0 = kr[0][j], s1 = kr[1][j], s2 = kr[2][j], s3 = kr[3][j];
      float u0 = (s0 >= tf0) ? rintf(exp2f(__builtin_fmaf(s0, 1.44269504f, LOG2C))) : 0.f;
      float u1 = (s1 >= tf1) ? rintf(exp2f(__builtin_fmaf(s1, 1.44269504f, LOG2C))) : 0.f;
      float u2 = (s2 >= tf2) ? rintf(exp2f(__builtin_fmaf(s2, 1.44269504f, LOG2C))) : 0.f;
      float u3 = (s3 >= tf3) ? rintf(exp2f(__builtin_fmaf(s3, 1.44269504f, LOG2C))) : 0.f;
      id0 += (unsigned)u0; id1 += (unsigned)u1;
      id2 += (unsigned)u2; id3 += (unsigned)u3;
#if USE_DOT2
      pk[(t << 1) + 0] = asu32(__builtin_amdgcn_cvt_pkrtz(u0, u1));
      pk[(t << 1) + 1] = asu32(__builtin_amdgcn_cvt_pkrtz(u2, u3));
#else
      { f16x2 a; a[0] = (__fp16)u0; a[1] = (__fp16)u1; pk[(t << 1) + 0] = asu32(a); }
      { f16x2 b; b[0] = (__fp16)u2; b[1] = (__fp16)u3; pk[(t << 1) + 1] = asu32(b); }
#endif
    }
    const int col = (g << 10) + cb;            // addr = col*8, 16B-aligned
    *(uint4*)&wts2[col][0]     = make_uint4(pk[0], pk[1], pk[2], pk[3]);
    *(uint4*)&wts2[col + 2][0] = make_uint4(pk[4], pk[5], pk[6], pk[7]);
  }
  // exact integer denominators: wave-reduce then cross-wave sum
#pragma unroll
  for (int s = 1; s < 64; s <<= 1) {
    id0 += __shfl_xor(id0, s); id1 += __shfl_xor(id1, s);
    id2 += __shfl_xor(id2, s); id3 += __shfl_xor(id3, s);
  }
  if (lane == 0) *(uint4*)&dred[wv][0] = make_uint4(id0, id1, id2, id3);
  __syncthreads();  // wts2 + dred visible to all
  const float dnm0 = (float)(dred[0][0] + dred[1][0] + dred[2][0] + dred[3][0]);
  const float dnm1 = (float)(dred[0][1] + dred[1][1] + dred[2][1] + dred[3][1]);
  const float dnm2 = (float)(dred[0][2] + dred[1][2] + dred[2][2] + dred[3][2]);
  const float dnm3 = (float)(dred[0][3] + dred[1][3] + dred[2][3] + dred[3][3]);

  // phase 5: PV via pk_fma over d-pairs, all-fp16 operands (convert-once).
  // Weight splats via shufflevector -> op_sel folding (no dup insts).
  // wave wv covers m in [wv*1024, +1024); lane-group mg owns m stride 8,
  // slot5 owns d-quad. Per m: 1 ds_read_b64 (w, broadcast over 8 lanes,
  // conflict-free) + 1 global b64 (V16 4d slice) + 8 v_pk_fma_f16.
  const int slot5 = lane & 7, mg = lane >> 3;
  const int mbase = wv << 10;
  f16x2 av2[4][2];
#pragma unroll
  for (int r = 0; r < 4; ++r)
#pragma unroll
    for (int c = 0; c < 2; ++c) { av2[r][c][0] = (__fp16)0.f; av2[r][c][1] = (__fp16)0.f; }

#pragma unroll 4
  for (int ii = 0; ii < 128; ++ii) {
    const int m = mbase + (ii << 3) + mg;
    const f16x4v wq = *(const f16x4v*)&wts2[m][0];       // w0,w1,w2,w3
    const f16x4v vv = *(const f16x4v*)(Vh + m * HD + (slot5 << 2));
    const f16x2 va = __builtin_shufflevector(vv, vv, 0, 1);
    const f16x2 vb = __builtin_shufflevector(vv, vv, 2, 3);
    const f16x2 w00 = __builtin_shufflevector(wq, wq, 0, 0);
    const f16x2 w11 = __builtin_shufflevector(wq, wq, 1, 1);
    const f16x2 w22 = __builtin_shufflevector(wq, wq, 2, 2);
    const f16x2 w33 = __builtin_shufflevector(wq, wq, 3, 3);
    av2[0][0] += w00 * va; av2[0][1] += w00 * vb;
    av2[1][0] += w11 * va; av2[1][1] += w11 * vb;
    av2[2][0] += w22 * va; av2[2][1] += w22 * vb;
    av2[3][0] += w33 * va; av2[3][1] += w33 * vb;
  }
  // convert to fp32 and reduce over mg (lane bits 3..5)
  float av[4][4];
#pragma unroll
  for (int r = 0; r < 4; ++r) {
    av[r][0] = (float)av2[r][0][0]; av[r][1] = (float)av2[r][0][1];
    av[r][2] = (float)av2[r][1][0]; av[r][3] = (float)av2[r][1][1];
  }
#pragma unroll
  for (int r = 0; r < 4; ++r)
#pragma unroll
    for (int c = 0; c < 4; ++c) {
      float x = av[r][c];
      x += __shfl_xor(x, 8); x += __shfl_xor(x, 16); x += __shfl_xor(x, 32);
      av[r][c] = x;
    }
  if (mg == 0) {
#pragma unroll
    for (int r = 0; r < 4; ++r)
#pragma unroll
      for (int c = 0; c < 4; ++c)
        pvred[(((wv << 3) + slot5) * 4 + r) * 4 + c] = av[r][c];
  }
  __syncthreads();

  if (tid < 128) {
    const int r = tid >> 5, d = tid & 31;
    const int sl = d >> 2, c = d & 3;
    float val = 0.f;
#pragma unroll
    for (int w = 0; w < 4; ++w) val += pvred[(((w << 3) + sl) * 4 + r) * 4 + c];
    float dn = (r == 0) ? dnm0 : (r == 1) ? dnm1 : (r == 2) ? dnm2 : dnm3;
    val /= dn;
    AO[(head * HD + d) * NTOK + n0 + r] = val;  // [C][N] for proj GEMM
  }
}

// ---- kernel 5: GroupNorm stats (32 groups of 8 ch x 4096 = 32768 vals) ----

__global__ __launch_bounds__(256) void gn_stats(const float* __restrict__ O,
                                                float* __restrict__ ST) {
  const int g = blockIdx.x, tid = threadIdx.x;
  const float4* p4 = (const float4*)(O + g * 32768);
  float s = 0.f, ss = 0.f;
  for (int i = tid; i < 8192; i += 256) {
    float4 v = p4[i];
    s += (v.x + v.y) + (v.z + v.w);
    ss += (v.x * v.x + v.y * v.y) + (v.z * v.z + v.w * v.w);
  }
#pragma unroll
  for (int m = 1; m < 64; m <<= 1) {
    s += __shfl_xor(s, m);
    ss += __shfl_xor(ss, m);
  }
  __shared__ float rs[4], rss[4];
  if ((tid & 63) == 0) { rs[tid >> 6] = s; rss[tid >> 6] = ss; }
  __syncthreads();
  if (tid == 0) {
    float S = rs[0] + rs[1] + rs[2] + rs[3];
    float SS = rss[0] + rss[1] + rss[2] + rss[3];
    float mean = S * (1.f / 32768.f);
    float var = SS * (1.f / 32768.f) - mean * mean;
    ST[g * 2] = mean;
    ST[g * 2 + 1] = rsqrtf(var + 1e-6f);
  }
}

// ---- kernel 6: GroupNorm apply (in place on d_out) ------------------------
// Indexes FLOAT4s: total 1048576/4 = 262144 -> grid 1024 x 256.

__global__ __launch_bounds__(256) void gn_apply(float* __restrict__ O,
                                                const float* __restrict__ ST,
                                                const float* __restrict__ gamma,
                                                const float* __restrict__ beta) {
  const int i4 = blockIdx.x * 256 + threadIdx.x;  // float4 index
  const int c = i4 >> 10, g = c >> 3;
  const float a = ST[g * 2 + 1] * gamma[c];
  const float b = beta[c] - ST[g * 2] * a;
  float4 v = *(float4*)(O + (i4 << 2));
  v.x = v.x * a + b; v.y = v.y * a + b; v.z = v.z * a + b; v.w = v.w * a + b;
  *(float4*)(O + (i4 << 2)) = v;
}

// ---- launch ---------------------------------------------------------------

extern "C" void kernel_launch(void* const* d_in, const int* in_sizes, int n_in,
                              void* d_out, int out_size, void* d_ws,
                              size_t ws_size, hipStream_t stream) {
  const float* x = (const float*)d_in[0];       // [256][4096]
  const float* w_qkv = (const float*)d_in[1];   // [768][256]
  const float* w_proj = (const float*)d_in[2];  // [256][256]
  const float* gamma = (const float*)d_in[3];   // [256]
  const float* beta = (const float*)d_in[4];    // [256]
  float* out = (float*)d_out;                   // [256][4096]

  float* Q = (float*)d_ws;          // [8][4096][32] fp32
  float* KT = Q + 1048576;          // [8][32][4096] fp32 -> fp16 pairs in place
  float* V16r = KT + 1048576;       // [8][4096][32] FP16 (2MB of the 4MB slot)
  float* AO = V16r + 1048576;       // [256][4096] fp32
  float* ST = AO + 1048576;         // [32][2]

  gemm_k256<true><<<dim3(64, 12), 256, 0, stream>>>(w_qkv, x, Q, KT, V16r);
  l2norm_kt_pack<<<dim3(16, 8), 256, 0, stream>>>(KT);
  attn_kernel<<<8192, 256, 0, stream>>>(Q, KT, (const __fp16*)V16r, AO);
  gemm_k256<false><<<dim3(64, 4), 256, 0, stream>>>(w_proj, AO, out, nullptr, nullptr);
  gn_stats<<<32, 256, 0, stream>>>(out, ST);
  gn_apply<<<1024, 256, 0, stream>>>(out, ST, gamma, beta);
}

// Round 18
// 421.367 us; speedup vs baseline: 1.0972x; 1.0104x over previous
//
#include <hip/hip_runtime.h>

// ---------------------------------------------------------------------------
// LowFreqSparseAttention: qkv 1x1conv -> l2norm(q,k) -> S=QK^T*scale ->
// top-k(k=N/2) mask -> softmax -> PV -> proj 1x1conv -> GroupNorm(32 groups).
// B=1, C=256, H=W=64 -> N=4096, 8 heads, hd=32, k_sel=2048.
//
// R31 = R30 (345us attn, best) + phase-5 REPARTITION (d-octet x 16 m-grp).
// R30 post-mortem: 4th consecutive confirmation that instruction removal is
// the only working lever (R28 grid: occ 41-51% neutral). Phase 5 is the
// largest remaining block (128 m-iters x 12 insts) with structural slack:
// per-iteration overhead amortized over only 8 pk_fma.
// Change: slot5 = lane&3 (8 d), mg = lane>>2 (16 m-groups, stride 16) ->
// 64 iters x {1 ds_read_b64 (16 distinct m x 8B = all banks, no conflict)
// + 1 b128 V load (wave reads 1KB contiguous) + 16 pk_fma + 2 addr}.
// Phase-5 issue 1536 -> ~1280 (-7% kernel); LDS reads halve. Accum 16
// f16x2 regs (still < phase-2 peak). Reduce over lane bits 2-5.
// Predict: attn ~325-335, total ~405-415, absmax 0.047 flat.
// Falsif.: attn >= 342 -> declare structural floor.
// ---------------------------------------------------------------------------

#define NTOK 4096
#define HD 32
#define NHEADS 8
#define KSEL 2048
#define SCALE 0.17677669529663689f   // 32^-0.5  (folded into fused q-norm)
#define LOG2C 7.73937f               // log2(255 / e^0.1767767)

typedef __fp16 f16x2 __attribute__((ext_vector_type(2)));
typedef __fp16 f16x4v __attribute__((ext_vector_type(4)));
typedef __fp16 f16x8v __attribute__((ext_vector_type(8)));

#define USE_DOT2 (__has_builtin(__builtin_amdgcn_fdot2) && \
                  __has_builtin(__builtin_amdgcn_cvt_pkrtz))

// ---- helpers --------------------------------------------------------------

__device__ __forceinline__ unsigned fkey(float f) {
  unsigned b = __float_as_uint(f);
  return (b & 0x80000000u) ? ~b : (b | 0x80000000u);
}
__device__ __forceinline__ float unfkey(unsigned k) {
  unsigned b = (k & 0x80000000u) ? (k ^ 0x80000000u) : ~k;
  return __uint_as_float(b);
}
__device__ __forceinline__ unsigned rfl_u(unsigned x) {  // force SGPR
  return __builtin_amdgcn_readfirstlane(x);
}
__device__ __forceinline__ f16x2 asv2h(unsigned u) {
  union { unsigned u; f16x2 h; } c; c.u = u; return c.h;
}
__device__ __forceinline__ unsigned asu32(f16x2 h) {
  union { f16x2 h; unsigned u; } c; c.h = h; return c.u;
}
// regula-falsi probe in key space, clamped to (klo, khi]
__device__ __forceinline__ unsigned probe_rf(unsigned klo, unsigned khi,
                                             float xlo, float xhi,
                                             int clo, int chi) {
  float t = xlo + (xhi - xlo) * ((float)(clo - KSEL) / (float)(clo - chi));
  unsigned k = fkey(t);
  if (k <= klo) k = klo + 1u;
  if (k > khi) k = khi;
  return k;
}

// ---- kernel 1/4: GEMM  C[M][4096] = A[M][256] * B[256][4096] --------------
// SCATTER: M=768 -> Q [h][n][d] fp32, KT [h][d][n] fp32 (transposed),
//          V16 [h][n][d] FP16 (scattered 2B stores).
// else:    M=256 -> plain row-major C0.

template <bool SCATTER>
__global__ __launch_bounds__(256) void gemm_k256(
    const float* __restrict__ A, const float* __restrict__ B,
    float* __restrict__ C0, float* __restrict__ C1, float* __restrict__ C2) {
  __shared__ float Wt[64][17];   // +1 pad: avoid 16-way bank conflict
  __shared__ float Xt[16][64];

  const int tid = threadIdx.x;
  const int tx = tid & 15, ty = tid >> 4;
  const int o0 = blockIdx.y * 64, n0 = blockIdx.x * 64;

  const int wr = tid >> 2, wc = (tid & 3) << 2;   // W-tile 64x16 loader
  const int xr = tid >> 4, xc = (tid & 15) << 2;  // X-tile 16x64 loader

  float4 acc[4];
#pragma unroll
  for (int i = 0; i < 4; ++i) acc[i] = make_float4(0.f, 0.f, 0.f, 0.f);

  for (int k0 = 0; k0 < 256; k0 += 16) {
    float4 wv = *(const float4*)(A + (o0 + wr) * 256 + k0 + wc);
    float4 xv = *(const float4*)(B + (k0 + xr) * 4096 + n0 + xc);
    Wt[wr][wc + 0] = wv.x; Wt[wr][wc + 1] = wv.y;
    Wt[wr][wc + 2] = wv.z; Wt[wr][wc + 3] = wv.w;
    *(float4*)&Xt[xr][xc] = xv;
    __syncthreads();
#pragma unroll
    for (int kk = 0; kk < 16; ++kk) {
      float4 b = *(const float4*)&Xt[kk][tx << 2];
#pragma unroll
      for (int i = 0; i < 4; ++i) {
        float a = Wt[(ty << 2) + i][kk];
        acc[i].x += a * b.x; acc[i].y += a * b.y;
        acc[i].z += a * b.z; acc[i].w += a * b.w;
      }
    }
    __syncthreads();
  }

  if (SCATTER) {
#pragma unroll
    for (int i = 0; i < 4; ++i) {
      int o = o0 + (ty << 2) + i;
      int which = o >> 8, rem = o & 255;
      int h = rem >> 5, d = rem & 31;
      int n = n0 + (tx << 2);
      if (which == 1) {
        // KT[h][d][n..n+3]: contiguous float4
        *(float4*)(C1 + h * (HD * NTOK) + d * NTOK + n) = acc[i];
      } else if (which == 2) {
        // V16[h][n][d]: fp16, scattered 2B stores
        __fp16* vh = (__fp16*)C2;
        int base = h * (NTOK * HD) + d;
        vh[base + (n + 0) * HD] = (__fp16)acc[i].x;
        vh[base + (n + 1) * HD] = (__fp16)acc[i].y;
        vh[base + (n + 2) * HD] = (__fp16)acc[i].z;
        vh[base + (n + 3) * HD] = (__fp16)acc[i].w;
      } else {
        // Q[h][n][d]: scattered fp32 (normalized in attn phase 1)
        int base = h * (NTOK * HD) + d;
        C0[base + (n + 0) * HD] = acc[i].x;
        C0[base + (n + 1) * HD] = acc[i].y;
        C0[base + (n + 2) * HD] = acc[i].z;
        C0[base + (n + 3) * HD] = acc[i].w;
      }
    }
  } else {
#pragma unroll
    for (int i = 0; i < 4; ++i) {
      int o = o0 + (ty << 2) + i;
      *(float4*)(C0 + o * 4096 + n0 + (tx << 2)) = acc[i];
    }
  }
}

// ---- kernel 2: l2norm KT columns + fp16 d-pair pack (in place) ------------
// Reads KT[h][d][n] (fp32, all 32 d at fixed n), normalizes, writes packed
// fp16 pairs K16[h][d2][n] = (k[2d2],k[2d2+1]) over KT's first 16 rows.
// Aliasing is column-local (thread reads its column fully before storing).

__global__ __launch_bounds__(256) void l2norm_kt_pack(float* __restrict__ KT) {
  const int n = blockIdx.x * 256 + threadIdx.x;
  float* P = KT + blockIdx.y * (HD * NTOK) + n;
  float v[HD];
  float ss = 0.f;
#pragma unroll
  for (int d = 0; d < HD; ++d) {
    v[d] = P[d * NTOK];          // coalesced across lanes
    ss += v[d] * v[d];
  }
  float inv = 1.f / fmaxf(sqrtf(ss), 1e-12f);
  unsigned* O = (unsigned*)P;    // in-place: rows 0..15 as pair words
#pragma unroll
  for (int d2 = 0; d2 < 16; ++d2) {
#if USE_DOT2
    O[d2 * NTOK] = asu32(
        __builtin_amdgcn_cvt_pkrtz(v[2 * d2] * inv, v[2 * d2 + 1] * inv));
#else
    f16x2 p; p[0] = (__fp16)(v[2 * d2] * inv); p[1] = (__fp16)(v[2 * d2 + 1] * inv);
    O[d2 * NTOK] = asu32(p);
#endif
  }
}

// ---- kernel 3: fused attention (4 rows per block, column-partitioned) -----
// phase1: stage 4 q rows with FUSED l2norm (32-lane shfl reduce, *SCALE),
//         then pack fp16 q d-pairs into LDS (once).
// phase2: thread tid owns cols {g*1024 + tid*4 + t}; 16 d2-iters of
//         {4 coalesced b128 K-pair loads + 4 broadcast b32 q-pair reads +
//          64 v_dot2_f32_f16} -> kr[4][16] fp32.
// phase3: hybrid selection (R19 window). Counts readfirstlane'd.
// phase4: fp16 weights wts2[m][4] (8B/col) -> two b128 stores per 4 cols;
//         exact integer denominators, block-reduced.
// phase5: PV via v_pk_fma_f16, d-OCTET x 16 m-group partition: 64 iters x
//         {1 ds_read_b64 + 1 b128 V load + 16 pk_fma}. Weight splats via
//         shufflevector (op_sel folding). fp16 accumulate, fp32 reduce.

__global__ __launch_bounds__(256, 5) void attn_kernel(
    const float* __restrict__ Q, const float* __restrict__ KT,
    const __fp16* __restrict__ V16, float* __restrict__ AO) {
  __shared__ __align__(16) __fp16 wts2[NTOK][4];          // 32 KB, [m][row]
  __shared__ float qs[128];
  __shared__ unsigned qs2u[4][16];                        // fp16 q d-pairs
  __shared__ float pvred[4 * 4 * 4 * 8];                  // 2 KB [wv][sl][r][do]
  __shared__ unsigned ired[2][4][2];                      // bisection dbuf
  __shared__ unsigned dred[4][4];                         // denom partials

  const int tid = threadIdx.x;
  const int wv = tid >> 6, lane = tid & 63;
  const int head = blockIdx.x & 7;          // head == blockIdx%8 -> XCD-pinned
  const int n0 = (blockIdx.x >> 3) << 2;

  const float* Qh = Q + head * (NTOK * HD);
  const float* KTh = KT + head * (HD * NTOK);
  const __fp16* Vh = V16 + head * (NTOK * HD);

  // phase 1: stage the block's 4 q rows with fused l2norm (each Q row is
  // read by exactly ONE block -> fusion is safe). Threads 0-127 span two
  // full waves; 32-lane xor-reduce = per-row sum of squares. Then pack
  // fp16 d-pairs (once per block).
  if (tid < 128) {
    float v = Qh[n0 * HD + tid];
    float ss = v * v;
#pragma unroll
    for (int m = 16; m >= 1; m >>= 1) ss += __shfl_xor(ss, m, 32);
    qs[tid] = v * SCALE / fmaxf(sqrtf(ss), 1e-12f);
  }
  __syncthreads();
  if (tid < 64) {
    const int r = tid >> 4, d2 = tid & 15;
#if USE_DOT2
    qs2u[r][d2] = asu32(__builtin_amdgcn_cvt_pkrtz(
        qs[r * HD + (d2 << 1)], qs[r * HD + (d2 << 1) + 1]));
#else
    f16x2 p; p[0] = (__fp16)qs[r * HD + (d2 << 1)];
    p[1] = (__fp16)qs[r * HD + (d2 << 1) + 1];
    qs2u[r][d2] = asu32(p);
#endif
  }
  __syncthreads();

  // phase 2: kr[r][g*4+t] = score(row r, col g*1024 + tid*4 + t) via dot2
  // over d-pairs. Each K pair-word read by exactly ONE thread of the block.
  float kr[4][16];
#pragma unroll
  for (int r = 0; r < 4; ++r)
#pragma unroll
    for (int j = 0; j < 16; ++j) kr[r][j] = 0.f;

  const int cb = tid << 2;
  const unsigned* k16 = (const unsigned*)KTh + cb;   // [16][NTOK] pair words
#pragma unroll 1
  for (int d2 = 0; d2 < 16; ++d2) {
    const unsigned* kp = k16 + d2 * NTOK;
    const uint4 kv0 = *(const uint4*)(kp);
    const uint4 kv1 = *(const uint4*)(kp + 1024);
    const uint4 kv2 = *(const uint4*)(kp + 2048);
    const uint4 kv3 = *(const uint4*)(kp + 3072);
    const unsigned qu0 = qs2u[0][d2], qu1 = qs2u[1][d2];
    const unsigned qu2 = qs2u[2][d2], qu3 = qs2u[3][d2];
#if USE_DOT2
    const f16x2 q0 = asv2h(qu0), q1 = asv2h(qu1);
    const f16x2 q2 = asv2h(qu2), q3 = asv2h(qu3);
#define DOT16(r, qv)                                                         \
    kr[r][0]  = __builtin_amdgcn_fdot2(qv, asv2h(kv0.x), kr[r][0],  false);  \
    kr[r][1]  = __builtin_amdgcn_fdot2(qv, asv2h(kv0.y), kr[r][1],  false);  \
    kr[r][2]  = __builtin_amdgcn_fdot2(qv, asv2h(kv0.z), kr[r][2],  false);  \
    kr[r][3]  = __builtin_amdgcn_fdot2(qv, asv2h(kv0.w), kr[r][3],  false);  \
    kr[r][4]  = __builtin_amdgcn_fdot2(qv, asv2h(kv1.x), kr[r][4],  false);  \
    kr[r][5]  = __builtin_amdgcn_fdot2(qv, asv2h(kv1.y), kr[r][5],  false);  \
    kr[r][6]  = __builtin_amdgcn_fdot2(qv, asv2h(kv1.z), kr[r][6],  false);  \
    kr[r][7]  = __builtin_amdgcn_fdot2(qv, asv2h(kv1.w), kr[r][7],  false);  \
    kr[r][8]  = __builtin_amdgcn_fdot2(qv, asv2h(kv2.x), kr[r][8],  false);  \
    kr[r][9]  = __builtin_amdgcn_fdot2(qv, asv2h(kv2.y), kr[r][9],  false);  \
    kr[r][10] = __builtin_amdgcn_fdot2(qv, asv2h(kv2.z), kr[r][10], false);  \
    kr[r][11] = __builtin_amdgcn_fdot2(qv, asv2h(kv2.w), kr[r][11], false);  \
    kr[r][12] = __builtin_amdgcn_fdot2(qv, asv2h(kv3.x), kr[r][12], false);  \
    kr[r][13] = __builtin_amdgcn_fdot2(qv, asv2h(kv3.y), kr[r][13], false);  \
    kr[r][14] = __builtin_amdgcn_fdot2(qv, asv2h(kv3.z), kr[r][14], false);  \
    kr[r][15] = __builtin_amdgcn_fdot2(qv, asv2h(kv3.w), kr[r][15], false);
    DOT16(0, q0) DOT16(1, q1) DOT16(2, q2) DOT16(3, q3)
#undef DOT16
#else
#define DOTF(r, qu)                                                          \
    {                                                                        \
      const f16x2 qq = asv2h(qu);                                            \
      const float qa = (float)qq[0], qb = (float)qq[1];                      \
      const unsigned kk[16] = {kv0.x, kv0.y, kv0.z, kv0.w, kv1.x, kv1.y,     \
                               kv1.z, kv1.w, kv2.x, kv2.y, kv2.z, kv2.w,     \
                               kv3.x, kv3.y, kv3.z, kv3.w};                  \
      _Pragma("unroll")                                                      \
      for (int j = 0; j < 16; ++j) {                                         \
        const f16x2 kh = asv2h(kk[j]);                                       \
        kr[r][j] += qa * (float)kh[0] + qb * (float)kh[1];                   \
      }                                                                      \
    }
    DOTF(0, qu0) DOTF(1, qu1) DOTF(2, qu2) DOTF(3, qu3)
#undef DOTF
#endif
  }

  // phase 3: hybrid selection per row (R19 schedule). Bracket invariant
  // (key space): count(klo) >= KSEL, answer in [klo, khi]. RF probe while
  // it<8 && width>65536; ulp midpoint after. Exit on count==KSEL (kept set
  // == top-k of the COMPUTED scores; ties make the count skip KSEL so
  // ==KSEL is tie-free) or klo==khi (exact kth key).
  // |scores| <= 0.1768 < 0.25, so anchors (-0.25 -> 4096, +0.25 -> 0).
  // State block-uniform; counts readfirstlane'd -> SGPR/SALU resident.
  unsigned klo0 = 0x417FFFFFu, khi0 = 0xBE800000u;  // fkey(-.25), fkey(.25)
  unsigned klo1 = 0x417FFFFFu, khi1 = 0xBE800000u;
  unsigned klo2 = 0x417FFFFFu, khi2 = 0xBE800000u;
  unsigned klo3 = 0x417FFFFFu, khi3 = 0xBE800000u;
  float xlo0 = -0.25f, xhi0 = 0.25f, xlo1 = -0.25f, xhi1 = 0.25f;
  float xlo2 = -0.25f, xhi2 = 0.25f, xlo3 = -0.25f, xhi3 = 0.25f;
  int clo0 = NTOK, chi0 = 0, clo1 = NTOK, chi1 = 0;
  int clo2 = NTOK, chi2 = 0, clo3 = NTOK, chi3 = 0;
  bool dn0 = false, dn1 = false, dn2 = false, dn3 = false;
  int slot = 0;
#pragma unroll 1
  for (int it = 0; it < 40; ++it) {
    unsigned m0 = dn0 ? klo0
        : ((it < 8 && (khi0 - klo0) > 65536u)
               ? rfl_u(probe_rf(klo0, khi0, xlo0, xhi0, clo0, chi0))
               : klo0 + ((khi0 - klo0 + 1u) >> 1));
    unsigned m1 = dn1 ? klo1
        : ((it < 8 && (khi1 - klo1) > 65536u)
               ? rfl_u(probe_rf(klo1, khi1, xlo1, xhi1, clo1, chi1))
               : klo1 + ((khi1 - klo1 + 1u) >> 1));
    unsigned m2 = dn2 ? klo2
        : ((it < 8 && (khi2 - klo2) > 65536u)
               ? rfl_u(probe_rf(klo2, khi2, xlo2, xhi2, clo2, chi2))
               : klo2 + ((khi2 - klo2 + 1u) >> 1));
    unsigned m3 = dn3 ? klo3
        : ((it < 8 && (khi3 - klo3) > 65536u)
               ? rfl_u(probe_rf(klo3, khi3, xlo3, xhi3, clo3, chi3))
               : klo3 + ((khi3 - klo3 + 1u) >> 1));
    unsigned c0 = 0, c1 = 0, c2 = 0, c3 = 0;
    if (!dn0) {
      const float f0 = unfkey(m0);
#pragma unroll
      for (int j = 0; j < 16; ++j) c0 += __popcll(__ballot(kr[0][j] >= f0));
    }
    if (!dn1) {
      const float f1 = unfkey(m1);
#pragma unroll
      for (int j = 0; j < 16; ++j) c1 += __popcll(__ballot(kr[1][j] >= f1));
    }
    if (!dn2) {
      const float f2 = unfkey(m2);
#pragma unroll
      for (int j = 0; j < 16; ++j) c2 += __popcll(__ballot(kr[2][j] >= f2));
    }
    if (!dn3) {
      const float f3 = unfkey(m3);
#pragma unroll
      for (int j = 0; j < 16; ++j) c3 += __popcll(__ballot(kr[3][j] >= f3));
    }
    if (lane == 0) {
      ired[slot][wv][0] = c0 | (c1 << 16);
      ired[slot][wv][1] = c2 | (c3 << 16);
    }
    __syncthreads();
    unsigned a01 = rfl_u(ired[slot][0][0] + ired[slot][1][0] +
                         ired[slot][2][0] + ired[slot][3][0]);
    unsigned a23 = rfl_u(ired[slot][0][1] + ired[slot][1][1] +
                         ired[slot][2][1] + ired[slot][3][1]);
    slot ^= 1;
    int C0 = (int)(a01 & 0xFFFFu), C1 = (int)(a01 >> 16);
    int C2 = (int)(a23 & 0xFFFFu), C3 = (int)(a23 >> 16);
#define BUPD(C, klo, khi, xlo, xhi, clo, chi, dn, mk)                        \
    if (!dn) {                                                               \
      if (C == KSEL) { klo = mk; dn = true; }                                \
      else if (C > KSEL) { klo = mk; xlo = unfkey(mk); clo = C; }            \
      else { khi = mk - 1u; xhi = unfkey(mk); chi = C; }                     \
      if (klo >= khi) dn = true;                                             \
    }
    BUPD(C0, klo0, khi0, xlo0, xhi0, clo0, chi0, dn0, m0)
    BUPD(C1, klo1, khi1, xlo1, xhi1, clo1, chi1, dn1, m1)
    BUPD(C2, klo2, khi2, xlo2, xhi2, clo2, chi2, dn2, m2)
    BUPD(C3, klo3, khi3, xlo3, xhi3, clo3, chi3, dn3, m3)
#undef BUPD
    if (dn0 && dn1 && dn2 && dn3) break;   // uniform across block
  }
  const float tf0 = unfkey(klo0), tf1 = unfkey(klo1);
  const float tf2 = unfkey(klo2), tf3 = unfkey(klo3);

  // phase 4: fp16 weights wts2[m][4] (8B per column). u = rint(exp(s) *
  // 255/e^smax) in [179,255] kept, 0 masked; integers exact in fp16.
  // Thread's 4 consecutive cols = 32B contiguous -> two b128 stores.
  unsigned id0 = 0, id1 = 0, id2 = 0, id3 = 0;
#pragma unroll
  for (int g = 0; g < 4; ++g) {
    unsigned pk[8];
#pragma unroll
    for (int t = 0; t < 4; ++t) {
      const int j = (g << 2) + t;
      float s0 = kr[0][j], s1 = kr[1][j], s2 = kr[2][j], s3 = kr[3][j];
      float u0 = (s0 >= tf0) ? rintf(exp2f(__builtin_fmaf(s0, 1.44269504f, LOG2C))) : 0.f;
      float u1 = (s1 >= tf1) ? rintf(exp2f(__builtin_fmaf(s1, 1.44269504f, LOG2C))) : 0.f;
      float u2 = (s2 >= tf2) ? rintf(exp2f(__builtin_fmaf(s2, 1.44269504f, LOG2C))) : 0.f;
      float u3 = (s3 >= tf3) ? rintf(exp2f(__builtin_fmaf(s3, 1.44269504f, LOG2C))) : 0.f;
      id0 += (unsigned)u0; id1 += (unsigned)u1;
      id2 += (unsigned)u2; id3 += (unsigned)u3;
#if USE_DOT2
      pk[(t << 1) + 0] = asu32(__builtin_amdgcn_cvt_pkrtz(u0, u1));
      pk[(t << 1) + 1] = asu32(__builtin_amdgcn_cvt_pkrtz(u2, u3));
#else
      { f16x2 a; a[0] = (__fp16)u0; a[1] = (__fp16)u1; pk[(t << 1) + 0] = asu32(a); }
      { f16x2 b; b[0] = (__fp16)u2; b[1] = (__fp16)u3; pk[(t << 1) + 1] = asu32(b); }
#endif
    }
    const int col = (g << 10) + cb;            // addr = col*8, 16B-aligned
    *(uint4*)&wts2[col][0]     = make_uint4(pk[0], pk[1], pk[2], pk[3]);
    *(uint4*)&wts2[col + 2][0] = make_uint4(pk[4], pk[5], pk[6], pk[7]);
  }
  // exact integer denominators: wave-reduce then cross-wave sum
#pragma unroll
  for (int s = 1; s < 64; s <<= 1) {
    id0 += __shfl_xor(id0, s); id1 += __shfl_xor(id1, s);
    id2 += __shfl_xor(id2, s); id3 += __shfl_xor(id3, s);
  }
  if (lane == 0) *(uint4*)&dred[wv][0] = make_uint4(id0, id1, id2, id3);
  __syncthreads();  // wts2 + dred visible to all
  const float dnm0 = (float)(dred[0][0] + dred[1][0] + dred[2][0] + dred[3][0]);
  const float dnm1 = (float)(dred[0][1] + dred[1][1] + dred[2][1] + dred[3][1]);
  const float dnm2 = (float)(dred[0][2] + dred[1][2] + dred[2][2] + dred[3][2]);
  const float dnm3 = (float)(dred[0][3] + dred[1][3] + dred[2][3] + dred[3][3]);

  // phase 5: PV via pk_fma, d-octet x 16 m-group partition (convert-once
  // fp16 operands; splats via shufflevector -> op_sel). Wave wv covers m
  // in [wv*1024, +1024): slot5 = lane&3 owns d [slot5*8, +8); mg = lane>>2
  // owns m stride 16. 64 iters x {1 ds_read_b64 (16 distinct m x 8B =
  // all banks, conflict-free) + 1 b128 V load (wave: 1KB contiguous) +
  // 16 pk_fma}.
  const int slot5 = lane & 3, mg = lane >> 2;
  const int mbase = wv << 10;
  f16x2 av2[4][4];   // [row][d-pair within octet]
#pragma unroll
  for (int r = 0; r < 4; ++r)
#pragma unroll
    for (int c = 0; c < 4; ++c) { av2[r][c][0] = (__fp16)0.f; av2[r][c][1] = (__fp16)0.f; }

#pragma unroll 4
  for (int ii = 0; ii < 64; ++ii) {
    const int m = mbase + (ii << 4) + mg;
    const f16x4v wq = *(const f16x4v*)&wts2[m][0];       // w0,w1,w2,w3
    const f16x8v vv = *(const f16x8v*)(Vh + m * HD + (slot5 << 3));
    const f16x2 va = __builtin_shufflevector(vv, vv, 0, 1);
    const f16x2 vb = __builtin_shufflevector(vv, vv, 2, 3);
    const f16x2 vc = __builtin_shufflevector(vv, vv, 4, 5);
    const f16x2 vd = __builtin_shufflevector(vv, vv, 6, 7);
    const f16x2 w00 = __builtin_shufflevector(wq, wq, 0, 0);
    const f16x2 w11 = __builtin_shufflevector(wq, wq, 1, 1);
    const f16x2 w22 = __builtin_shufflevector(wq, wq, 2, 2);
    const f16x2 w33 = __builtin_shufflevector(wq, wq, 3, 3);
    av2[0][0] += w00 * va; av2[0][1] += w00 * vb;
    av2[0][2] += w00 * vc; av2[0][3] += w00 * vd;
    av2[1][0] += w11 * va; av2[1][1] += w11 * vb;
    av2[1][2] += w11 * vc; av2[1][3] += w11 * vd;
    av2[2][0] += w22 * va; av2[2][1] += w22 * vb;
    av2[2][2] += w22 * vc; av2[2][3] += w22 * vd;
    av2[3][0] += w33 * va; av2[3][1] += w33 * vb;
    av2[3][2] += w33 * vc; av2[3][3] += w33 * vd;
  }
  // convert to fp32 and reduce over mg (lane bits 2..5)
  float av[4][8];
#pragma unroll
  for (int r = 0; r < 4; ++r)
#pragma unroll
    for (int c = 0; c < 4; ++c) {
      av[r][(c << 1) + 0] = (float)av2[r][c][0];
      av[r][(c << 1) + 1] = (float)av2[r][c][1];
    }
#pragma unroll
  for (int r = 0; r < 4; ++r)
#pragma unroll
    for (int c = 0; c < 8; ++c) {
      float x = av[r][c];
      x += __shfl_xor(x, 4); x += __shfl_xor(x, 8);
      x += __shfl_xor(x, 16); x += __shfl_xor(x, 32);
      av[r][c] = x;
    }
  if (mg == 0) {
#pragma unroll
    for (int r = 0; r < 4; ++r)
#pragma unroll
      for (int c = 0; c < 8; ++c)
        pvred[(((wv << 2) + slot5) * 4 + r) * 8 + c] = av[r][c];
  }
  __syncthreads();

  if (tid < 128) {
    const int r = tid >> 5, d = tid & 31;
    const int sl = d >> 3, c = d & 7;
    float val = 0.f;
#pragma unroll
    for (int w = 0; w < 4; ++w) val += pvred[(((w << 2) + sl) * 4 + r) * 8 + c];
    float dn = (r == 0) ? dnm0 : (r == 1) ? dnm1 : (r == 2) ? dnm2 : dnm3;
    val /= dn;
    AO[(head * HD + d) * NTOK + n0 + r] = val;  // [C][N] for proj GEMM
  }
}

// ---- kernel 5: GroupNorm stats (32 groups of 8 ch x 4096 = 32768 vals) ----

__global__ __launch_bounds__(256) void gn_stats(const float* __restrict__ O,
                                                float* __restrict__ ST) {
  const int g = blockIdx.x, tid = threadIdx.x;
  const float4* p4 = (const float4*)(O + g * 32768);
  float s = 0.f, ss = 0.f;
  for (int i = tid; i < 8192; i += 256) {
    float4 v = p4[i];
    s += (v.x + v.y) + (v.z + v.w);
    ss += (v.x * v.x + v.y * v.y) + (v.z * v.z + v.w * v.w);
  }
#pragma unroll
  for (int m = 1; m < 64; m <<= 1) {
    s += __shfl_xor(s, m);
    ss += __shfl_xor(ss, m);
  }
  __shared__ float rs[4], rss[4];
  if ((tid & 63) == 0) { rs[tid >> 6] = s; rss[tid >> 6] = ss; }
  __syncthreads();
  if (tid == 0) {
    float S = rs[0] + rs[1] + rs[2] + rs[3];
    float SS = rss[0] + rss[1] + rss[2] + rss[3];
    float mean = S * (1.f / 32768.f);
    float var = SS * (1.f / 32768.f) - mean * mean;
    ST[g * 2] = mean;
    ST[g * 2 + 1] = rsqrtf(var + 1e-6f);
  }
}

// ---- kernel 6: GroupNorm apply (in place on d_out) ------------------------
// Indexes FLOAT4s: total 1048576/4 = 262144 -> grid 1024 x 256.

__global__ __launch_bounds__(256) void gn_apply(float* __restrict__ O,
                                                const float* __restrict__ ST,
                                                const float* __restrict__ gamma,
                                                const float* __restrict__ beta) {
  const int i4 = blockIdx.x * 256 + threadIdx.x;  // float4 index
  const int c = i4 >> 10, g = c >> 3;
  const float a = ST[g * 2 + 1] * gamma[c];
  const float b = beta[c] - ST[g * 2] * a;
  float4 v = *(float4*)(O + (i4 << 2));
  v.x = v.x * a + b; v.y = v.y * a + b; v.z = v.z * a + b; v.w = v.w * a + b;
  *(float4*)(O + (i4 << 2)) = v;
}

// ---- launch ---------------------------------------------------------------

extern "C" void kernel_launch(void* const* d_in, const int* in_sizes, int n_in,
                              void* d_out, int out_size, void* d_ws,
                              size_t ws_size, hipStream_t stream) {
  const float* x = (const float*)d_in[0];       // [256][4096]
  const float* w_qkv = (const float*)d_in[1];   // [768][256]
  const float* w_proj = (const float*)d_in[2];  // [256][256]
  const float* gamma = (const float*)d_in[3];   // [256]
  const float* beta = (const float*)d_in[4];    // [256]
  float* out = (float*)d_out;                   // [256][4096]

  float* Q = (float*)d_ws;          // [8][4096][32] fp32
  float* KT = Q + 1048576;          // [8][32][4096] fp32 -> fp16 pairs in place
  float* V16r = KT + 1048576;       // [8][4096][32] FP16 (2MB of the 4MB slot)
  float* AO = V16r + 1048576;       // [256][4096] fp32
  float* ST = AO + 1048576;         // [32][2]

  gemm_k256<true><<<dim3(64, 12), 256, 0, stream>>>(w_qkv, x, Q, KT, V16r);
  l2norm_kt_pack<<<dim3(16, 8), 256, 0, stream>>>(KT);
  attn_kernel<<<8192, 256, 0, stream>>>(Q, KT, (const __fp16*)V16r, AO);
  gemm_k256<false><<<dim3(64, 4), 256, 0, stream>>>(w_proj, AO, out, nullptr, nullptr);
  gn_stats<<<32, 256, 0, stream>>>(out, ST);
  gn_apply<<<1024, 256, 0, stream>>>(out, ST, gamma, beta);
}

// Round 19
// 418.671 us; speedup vs baseline: 1.1043x; 1.0064x over previous
//
#include <hip/hip_runtime.h>

// ---------------------------------------------------------------------------
// LowFreqSparseAttention: qkv 1x1conv -> l2norm(q,k) -> S=QK^T*scale ->
// top-k(k=N/2) mask -> softmax -> PV -> proj 1x1conv -> GroupNorm(32 groups).
// B=1, C=256, H=W=64 -> N=4096, 8 heads, hd=32, k_sel=2048.
//
// R32 = R31 (338us attn / 421 total, best) + GEMM W-tile vectorization.
// R31 post-mortem: attn gains now ~2%/round; per-thread issue is near the
// algorithmic floor at this precision (phase2 pure dot2, phase5 pure
// pk_fma, phase3 probe schedule tuned flat both directions). Remaining
// mass: non-attn kernels ~83us, QKV GEMM ~45us of it. Its inner loop is
// LDS-issue-heavy: 64 scalar ds_read_b32 (W) + 16 ds_read_b128 (X) per
// k-step -- W is scalar only because the +1 pad (17-float rows) breaks
// 16B alignment.
// Change: Wt[64][20] (80B rows, 16B-aligned) -> W-tile store and reads
// become float4; inner loop reads 4 b128 W-rows per 4-kk group
// (compile-time component select). LDS ops/k-step 80 -> 20. Both GEMM
// instantiations benefit. Attn kernel untouched.
// Predict: total ~408-415, attn flat ~338, absmax 0.047 flat.
// Falsif.: total >= 419 -> GEMM not issue-bound -> declare roofline.
// ---------------------------------------------------------------------------

#define NTOK 4096
#define HD 32
#define NHEADS 8
#define KSEL 2048
#define SCALE 0.17677669529663689f   // 32^-0.5  (folded into fused q-norm)
#define LOG2C 7.73937f               // log2(255 / e^0.1767767)

typedef __fp16 f16x2 __attribute__((ext_vector_type(2)));
typedef __fp16 f16x4v __attribute__((ext_vector_type(4)));
typedef __fp16 f16x8v __attribute__((ext_vector_type(8)));

#define USE_DOT2 (__has_builtin(__builtin_amdgcn_fdot2) && \
                  __has_builtin(__builtin_amdgcn_cvt_pkrtz))

// ---- helpers --------------------------------------------------------------

__device__ __forceinline__ unsigned fkey(float f) {
  unsigned b = __float_as_uint(f);
  return (b & 0x80000000u) ? ~b : (b | 0x80000000u);
}
__device__ __forceinline__ float unfkey(unsigned k) {
  unsigned b = (k & 0x80000000u) ? (k ^ 0x80000000u) : ~k;
  return __uint_as_float(b);
}
__device__ __forceinline__ unsigned rfl_u(unsigned x) {  // force SGPR
  return __builtin_amdgcn_readfirstlane(x);
}
__device__ __forceinline__ f16x2 asv2h(unsigned u) {
  union { unsigned u; f16x2 h; } c; c.u = u; return c.h;
}
__device__ __forceinline__ unsigned asu32(f16x2 h) {
  union { f16x2 h; unsigned u; } c; c.h = h; return c.u;
}
// regula-falsi probe in key space, clamped to (klo, khi]
__device__ __forceinline__ unsigned probe_rf(unsigned klo, unsigned khi,
                                             float xlo, float xhi,
                                             int clo, int chi) {
  float t = xlo + (xhi - xlo) * ((float)(clo - KSEL) / (float)(clo - chi));
  unsigned k = fkey(t);
  if (k <= klo) k = klo + 1u;
  if (k > khi) k = khi;
  return k;
}

// ---- kernel 1/4: GEMM  C[M][4096] = A[M][256] * B[256][4096] --------------
// SCATTER: M=768 -> Q [h][n][d] fp32, KT [h][d][n] fp32 (transposed),
//          V16 [h][n][d] FP16 (scattered 2B stores).
// else:    M=256 -> plain row-major C0.
// Wt pad 20 (80B rows, 16B-aligned) -> W-tile traffic is all float4:
// LDS ops per k-step 80 -> 20 (4 W b128 + 16 X b128).

#define GSEL(v, t) ((t) == 0 ? (v).x : (t) == 1 ? (v).y : (t) == 2 ? (v).z : (v).w)

template <bool SCATTER>
__global__ __launch_bounds__(256) void gemm_k256(
    const float* __restrict__ A, const float* __restrict__ B,
    float* __restrict__ C0, float* __restrict__ C1, float* __restrict__ C2) {
  __shared__ float Wt[64][20];   // pad 4: rows 16B-aligned, vector W reads
  __shared__ float Xt[16][64];

  const int tid = threadIdx.x;
  const int tx = tid & 15, ty = tid >> 4;
  const int o0 = blockIdx.y * 64, n0 = blockIdx.x * 64;

  const int wr = tid >> 2, wc = (tid & 3) << 2;   // W-tile 64x16 loader
  const int xr = tid >> 4, xc = (tid & 15) << 2;  // X-tile 16x64 loader

  float4 acc[4];
#pragma unroll
  for (int i = 0; i < 4; ++i) acc[i] = make_float4(0.f, 0.f, 0.f, 0.f);

  for (int k0 = 0; k0 < 256; k0 += 16) {
    float4 wv = *(const float4*)(A + (o0 + wr) * 256 + k0 + wc);
    float4 xv = *(const float4*)(B + (k0 + xr) * 4096 + n0 + xc);
    *(float4*)&Wt[wr][wc] = wv;            // 16B-aligned (80B rows)
    *(float4*)&Xt[xr][xc] = xv;
    __syncthreads();
#pragma unroll
    for (int kk4 = 0; kk4 < 16; kk4 += 4) {
      const float4 w0 = *(const float4*)&Wt[(ty << 2) + 0][kk4];
      const float4 w1 = *(const float4*)&Wt[(ty << 2) + 1][kk4];
      const float4 w2 = *(const float4*)&Wt[(ty << 2) + 2][kk4];
      const float4 w3 = *(const float4*)&Wt[(ty << 2) + 3][kk4];
#pragma unroll
      for (int t = 0; t < 4; ++t) {
        const float4 b = *(const float4*)&Xt[kk4 + t][tx << 2];
        const float a0 = GSEL(w0, t), a1 = GSEL(w1, t);
        const float a2 = GSEL(w2, t), a3 = GSEL(w3, t);
        acc[0].x += a0 * b.x; acc[0].y += a0 * b.y;
        acc[0].z += a0 * b.z; acc[0].w += a0 * b.w;
        acc[1].x += a1 * b.x; acc[1].y += a1 * b.y;
        acc[1].z += a1 * b.z; acc[1].w += a1 * b.w;
        acc[2].x += a2 * b.x; acc[2].y += a2 * b.y;
        acc[2].z += a2 * b.z; acc[2].w += a2 * b.w;
        acc[3].x += a3 * b.x; acc[3].y += a3 * b.y;
        acc[3].z += a3 * b.z; acc[3].w += a3 * b.w;
      }
    }
    __syncthreads();
  }

  if (SCATTER) {
#pragma unroll
    for (int i = 0; i < 4; ++i) {
      int o = o0 + (ty << 2) + i;
      int which = o >> 8, rem = o & 255;
      int h = rem >> 5, d = rem & 31;
      int n = n0 + (tx << 2);
      if (which == 1) {
        // KT[h][d][n..n+3]: contiguous float4
        *(float4*)(C1 + h * (HD * NTOK) + d * NTOK + n) = acc[i];
      } else if (which == 2) {
        // V16[h][n][d]: fp16, scattered 2B stores
        __fp16* vh = (__fp16*)C2;
        int base = h * (NTOK * HD) + d;
        vh[base + (n + 0) * HD] = (__fp16)acc[i].x;
        vh[base + (n + 1) * HD] = (__fp16)acc[i].y;
        vh[base + (n + 2) * HD] = (__fp16)acc[i].z;
        vh[base + (n + 3) * HD] = (__fp16)acc[i].w;
      } else {
        // Q[h][n][d]: scattered fp32 (normalized in attn phase 1)
        int base = h * (NTOK * HD) + d;
        C0[base + (n + 0) * HD] = acc[i].x;
        C0[base + (n + 1) * HD] = acc[i].y;
        C0[base + (n + 2) * HD] = acc[i].z;
        C0[base + (n + 3) * HD] = acc[i].w;
      }
    }
  } else {
#pragma unroll
    for (int i = 0; i < 4; ++i) {
      int o = o0 + (ty << 2) + i;
      *(float4*)(C0 + o * 4096 + n0 + (tx << 2)) = acc[i];
    }
  }
}

// ---- kernel 2: l2norm KT columns + fp16 d-pair pack (in place) ------------
// Reads KT[h][d][n] (fp32, all 32 d at fixed n), normalizes, writes packed
// fp16 pairs K16[h][d2][n] = (k[2d2],k[2d2+1]) over KT's first 16 rows.
// Aliasing is column-local (thread reads its column fully before storing).

__global__ __launch_bounds__(256) void l2norm_kt_pack(float* __restrict__ KT) {
  const int n = blockIdx.x * 256 + threadIdx.x;
  float* P = KT + blockIdx.y * (HD * NTOK) + n;
  float v[HD];
  float ss = 0.f;
#pragma unroll
  for (int d = 0; d < HD; ++d) {
    v[d] = P[d * NTOK];          // coalesced across lanes
    ss += v[d] * v[d];
  }
  float inv = 1.f / fmaxf(sqrtf(ss), 1e-12f);
  unsigned* O = (unsigned*)P;    // in-place: rows 0..15 as pair words
#pragma unroll
  for (int d2 = 0; d2 < 16; ++d2) {
#if USE_DOT2
    O[d2 * NTOK] = asu32(
        __builtin_amdgcn_cvt_pkrtz(v[2 * d2] * inv, v[2 * d2 + 1] * inv));
#else
    f16x2 p; p[0] = (__fp16)(v[2 * d2] * inv); p[1] = (__fp16)(v[2 * d2 + 1] * inv);
    O[d2 * NTOK] = asu32(p);
#endif
  }
}

// ---- kernel 3: fused attention (4 rows per block, column-partitioned) -----
// phase1: stage 4 q rows with FUSED l2norm (32-lane shfl reduce, *SCALE),
//         then pack fp16 q d-pairs into LDS (once).
// phase2: thread tid owns cols {g*1024 + tid*4 + t}; 16 d2-iters of
//         {4 coalesced b128 K-pair loads + 4 broadcast b32 q-pair reads +
//          64 v_dot2_f32_f16} -> kr[4][16] fp32.
// phase3: hybrid selection (R19 window). Counts readfirstlane'd.
// phase4: fp16 weights wts2[m][4] (8B/col) -> two b128 stores per 4 cols;
//         exact integer denominators, block-reduced.
// phase5: PV via v_pk_fma_f16, d-OCTET x 16 m-group partition: 64 iters x
//         {1 ds_read_b64 + 1 b128 V load + 16 pk_fma}. Weight splats via
//         shufflevector (op_sel folding). fp16 accumulate, fp32 reduce.

__global__ __launch_bounds__(256, 5) void attn_kernel(
    const float* __restrict__ Q, const float* __restrict__ KT,
    const __fp16* __restrict__ V16, float* __restrict__ AO) {
  __shared__ __align__(16) __fp16 wts2[NTOK][4];          // 32 KB, [m][row]
  __shared__ float qs[128];
  __shared__ unsigned qs2u[4][16];                        // fp16 q d-pairs
  __shared__ float pvred[4 * 4 * 4 * 8];                  // 2 KB [wv][sl][r][do]
  __shared__ unsigned ired[2][4][2];                      // bisection dbuf
  __shared__ unsigned dred[4][4];                         // denom partials

  const int tid = threadIdx.x;
  const int wv = tid >> 6, lane = tid & 63;
  const int head = blockIdx.x & 7;          // head == blockIdx%8 -> XCD-pinned
  const int n0 = (blockIdx.x >> 3) << 2;

  const float* Qh = Q + head * (NTOK * HD);
  const float* KTh = KT + head * (HD * NTOK);
  const __fp16* Vh = V16 + head * (NTOK * HD);

  // phase 1: stage the block's 4 q rows with fused l2norm (each Q row is
  // read by exactly ONE block -> fusion is safe). Threads 0-127 span two
  // full waves; 32-lane xor-reduce = per-row sum of squares. Then pack
  // fp16 d-pairs (once per block).
  if (tid < 128) {
    float v = Qh[n0 * HD + tid];
    float ss = v * v;
#pragma unroll
    for (int m = 16; m >= 1; m >>= 1) ss += __shfl_xor(ss, m, 32);
    qs[tid] = v * SCALE / fmaxf(sqrtf(ss), 1e-12f);
  }
  __syncthreads();
  if (tid < 64) {
    const int r = tid >> 4, d2 = tid & 15;
#if USE_DOT2
    qs2u[r][d2] = asu32(__builtin_amdgcn_cvt_pkrtz(
        qs[r * HD + (d2 << 1)], qs[r * HD + (d2 << 1) + 1]));
#else
    f16x2 p; p[0] = (__fp16)qs[r * HD + (d2 << 1)];
    p[1] = (__fp16)qs[r * HD + (d2 << 1) + 1];
    qs2u[r][d2] = asu32(p);
#endif
  }
  __syncthreads();

  // phase 2: kr[r][g*4+t] = score(row r, col g*1024 + tid*4 + t) via dot2
  // over d-pairs. Each K pair-word read by exactly ONE thread of the block.
  float kr[4][16];
#pragma unroll
  for (int r = 0; r < 4; ++r)
#pragma unroll
    for (int j = 0; j < 16; ++j) kr[r][j] = 0.f;

  const int cb = tid << 2;
  const unsigned* k16 = (const unsigned*)KTh + cb;   // [16][NTOK] pair words
#pragma unroll 1
  for (int d2 = 0; d2 < 16; ++d2) {
    const unsigned* kp = k16 + d2 * NTOK;
    const uint4 kv0 = *(const uint4*)(kp);
    const uint4 kv1 = *(const uint4*)(kp + 1024);
    const uint4 kv2 = *(const uint4*)(kp + 2048);
    const uint4 kv3 = *(const uint4*)(kp + 3072);
    const unsigned qu0 = qs2u[0][d2], qu1 = qs2u[1][d2];
    const unsigned qu2 = qs2u[2][d2], qu3 = qs2u[3][d2];
#if USE_DOT2
    const f16x2 q0 = asv2h(qu0), q1 = asv2h(qu1);
    const f16x2 q2 = asv2h(qu2), q3 = asv2h(qu3);
#define DOT16(r, qv)                                                         \
    kr[r][0]  = __builtin_amdgcn_fdot2(qv, asv2h(kv0.x), kr[r][0],  false);  \
    kr[r][1]  = __builtin_amdgcn_fdot2(qv, asv2h(kv0.y), kr[r][1],  false);  \
    kr[r][2]  = __builtin_amdgcn_fdot2(qv, asv2h(kv0.z), kr[r][2],  false);  \
    kr[r][3]  = __builtin_amdgcn_fdot2(qv, asv2h(kv0.w), kr[r][3],  false);  \
    kr[r][4]  = __builtin_amdgcn_fdot2(qv, asv2h(kv1.x), kr[r][4],  false);  \
    kr[r][5]  = __builtin_amdgcn_fdot2(qv, asv2h(kv1.y), kr[r][5],  false);  \
    kr[r][6]  = __builtin_amdgcn_fdot2(qv, asv2h(kv1.z), kr[r][6],  false);  \
    kr[r][7]  = __builtin_amdgcn_fdot2(qv, asv2h(kv1.w), kr[r][7],  false);  \
    kr[r][8]  = __builtin_amdgcn_fdot2(qv, asv2h(kv2.x), kr[r][8],  false);  \
    kr[r][9]  = __builtin_amdgcn_fdot2(qv, asv2h(kv2.y), kr[r][9],  false);  \
    kr[r][10] = __builtin_amdgcn_fdot2(qv, asv2h(kv2.z), kr[r][10], false);  \
    kr[r][11] = __builtin_amdgcn_fdot2(qv, asv2h(kv2.w), kr[r][11], false);  \
    kr[r][12] = __builtin_amdgcn_fdot2(qv, asv2h(kv3.x), kr[r][12], false);  \
    kr[r][13] = __builtin_amdgcn_fdot2(qv, asv2h(kv3.y), kr[r][13], false);  \
    kr[r][14] = __builtin_amdgcn_fdot2(qv, asv2h(kv3.z), kr[r][14], false);  \
    kr[r][15] = __builtin_amdgcn_fdot2(qv, asv2h(kv3.w), kr[r][15], false);
    DOT16(0, q0) DOT16(1, q1) DOT16(2, q2) DOT16(3, q3)
#undef DOT16
#else
#define DOTF(r, qu)                                                          \
    {                                                                        \
      const f16x2 qq = asv2h(qu);                                            \
      const float qa = (float)qq[0], qb = (float)qq[1];                      \
      const unsigned kk[16] = {kv0.x, kv0.y, kv0.z, kv0.w, kv1.x, kv1.y,     \
                               kv1.z, kv1.w, kv2.x, kv2.y, kv2.z, kv2.w,     \
                               kv3.x, kv3.y, kv3.z, kv3.w};                  \
      _Pragma("unroll")                                                      \
      for (int j = 0; j < 16; ++j) {                                         \
        const f16x2 kh = asv2h(kk[j]);                                       \
        kr[r][j] += qa * (float)kh[0] + qb * (float)kh[1];                   \
      }                                                                      \
    }
    DOTF(0, qu0) DOTF(1, qu1) DOTF(2, qu2) DOTF(3, qu3)
#undef DOTF
#endif
  }

  // phase 3: hybrid selection per row (R19 schedule). Bracket invariant
  // (key space): count(klo) >= KSEL, answer in [klo, khi]. RF probe while
  // it<8 && width>65536; ulp midpoint after. Exit on count==KSEL (kept set
  // == top-k of the COMPUTED scores; ties make the count skip KSEL so
  // ==KSEL is tie-free) or klo==khi (exact kth key).
  // |scores| <= 0.1768 < 0.25, so anchors (-0.25 -> 4096, +0.25 -> 0).
  // State block-uniform; counts readfirstlane'd -> SGPR/SALU resident.
  unsigned klo0 = 0x417FFFFFu, khi0 = 0xBE800000u;  // fkey(-.25), fkey(.25)
  unsigned klo1 = 0x417FFFFFu, khi1 = 0xBE800000u;
  unsigned klo2 = 0x417FFFFFu, khi2 = 0xBE800000u;
  unsigned klo3 = 0x417FFFFFu, khi3 = 0xBE800000u;
  float xlo0 = -0.25f, xhi0 = 0.25f, xlo1 = -0.25f, xhi1 = 0.25f;
  float xlo2 = -0.25f, xhi2 = 0.25f, xlo3 = -0.25f, xhi3 = 0.25f;
  int clo0 = NTOK, chi0 = 0, clo1 = NTOK, chi1 = 0;
  int clo2 = NTOK, chi2 = 0, clo3 = NTOK, chi3 = 0;
  bool dn0 = false, dn1 = false, dn2 = false, dn3 = false;
  int slot = 0;
#pragma unroll 1
  for (int it = 0; it < 40; ++it) {
    unsigned m0 = dn0 ? klo0
        : ((it < 8 && (khi0 - klo0) > 65536u)
               ? rfl_u(probe_rf(klo0, khi0, xlo0, xhi0, clo0, chi0))
               : klo0 + ((khi0 - klo0 + 1u) >> 1));
    unsigned m1 = dn1 ? klo1
        : ((it < 8 && (khi1 - klo1) > 65536u)
               ? rfl_u(probe_rf(klo1, khi1, xlo1, xhi1, clo1, chi1))
               : klo1 + ((khi1 - klo1 + 1u) >> 1));
    unsigned m2 = dn2 ? klo2
        : ((it < 8 && (khi2 - klo2) > 65536u)
               ? rfl_u(probe_rf(klo2, khi2, xlo2, xhi2, clo2, chi2))
               : klo2 + ((khi2 - klo2 + 1u) >> 1));
    unsigned m3 = dn3 ? klo3
        : ((it < 8 && (khi3 - klo3) > 65536u)
               ? rfl_u(probe_rf(klo3, khi3, xlo3, xhi3, clo3, chi3))
               : klo3 + ((khi3 - klo3 + 1u) >> 1));
    unsigned c0 = 0, c1 = 0, c2 = 0, c3 = 0;
    if (!dn0) {
      const float f0 = unfkey(m0);
#pragma unroll
      for (int j = 0; j < 16; ++j) c0 += __popcll(__ballot(kr[0][j] >= f0));
    }
    if (!dn1) {
      const float f1 = unfkey(m1);
#pragma unroll
      for (int j = 0; j < 16; ++j) c1 += __popcll(__ballot(kr[1][j] >= f1));
    }
    if (!dn2) {
      const float f2 = unfkey(m2);
#pragma unroll
      for (int j = 0; j < 16; ++j) c2 += __popcll(__ballot(kr[2][j] >= f2));
    }
    if (!dn3) {
      const float f3 = unfkey(m3);
#pragma unroll
      for (int j = 0; j < 16; ++j) c3 += __popcll(__ballot(kr[3][j] >= f3));
    }
    if (lane == 0) {
      ired[slot][wv][0] = c0 | (c1 << 16);
      ired[slot][wv][1] = c2 | (c3 << 16);
    }
    __syncthreads();
    unsigned a01 = rfl_u(ired[slot][0][0] + ired[slot][1][0] +
                         ired[slot][2][0] + ired[slot][3][0]);
    unsigned a23 = rfl_u(ired[slot][0][1] + ired[slot][1][1] +
                         ired[slot][2][1] + ired[slot][3][1]);
    slot ^= 1;
    int C0 = (int)(a01 & 0xFFFFu), C1 = (int)(a01 >> 16);
    int C2 = (int)(a23 & 0xFFFFu), C3 = (int)(a23 >> 16);
#define BUPD(C, klo, khi, xlo, xhi, clo, chi, dn, mk)                        \
    if (!dn) {                                                               \
      if (C == KSEL) { klo = mk; dn = true; }                                \
      else if (C > KSEL) { klo = mk; xlo = unfkey(mk); clo = C; }            \
      else { khi = mk - 1u; xhi = unfkey(mk); chi = C; }                     \
      if (klo >= khi) dn = true;                                             \
    }
    BUPD(C0, klo0, khi0, xlo0, xhi0, clo0, chi0, dn0, m0)
    BUPD(C1, klo1, khi1, xlo1, xhi1, clo1, chi1, dn1, m1)
    BUPD(C2, klo2, khi2, xlo2, xhi2, clo2, chi2, dn2, m2)
    BUPD(C3, klo3, khi3, xlo3, xhi3, clo3, chi3, dn3, m3)
#undef BUPD
    if (dn0 && dn1 && dn2 && dn3) break;   // uniform across block
  }
  const float tf0 = unfkey(klo0), tf1 = unfkey(klo1);
  const float tf2 = unfkey(klo2), tf3 = unfkey(klo3);

  // phase 4: fp16 weights wts2[m][4] (8B per column). u = rint(exp(s) *
  // 255/e^smax) in [179,255] kept, 0 masked; integers exact in fp16.
  // Thread's 4 consecutive cols = 32B contiguous -> two b128 stores.
  unsigned id0 = 0, id1 = 0, id2 = 0, id3 = 0;
#pragma unroll
  for (int g = 0; g < 4; ++g) {
    unsigned pk[8];
#pragma unroll
    for (int t = 0; t < 4; ++t) {
      const int j = (g << 2) + t;
      float s0 = kr[0][j], s1 = kr[1][j], s2 = kr[2][j], s3 = kr[3][j];
      float u0 = (s0 >= tf0) ? rintf(exp2f(__builtin_fmaf(s0, 1.44269504f, LOG2C))) : 0.f;
      float u1 = (s1 >= tf1) ? rintf(exp2f(__builtin_fmaf(s1, 1.44269504f, LOG2C))) : 0.f;
      float u2 = (s2 >= tf2) ? rintf(exp2f(__builtin_fmaf(s2, 1.44269504f, LOG2C))) : 0.f;
      float u3 = (s3 >= tf3) ? rintf(exp2f(__builtin_fmaf(s3, 1.44269504f, LOG2C))) : 0.f;
      id0 += (unsigned)u0; id1 += (unsigned)u1;
      id2 += (unsigned)u2; id3 += (unsigned)u3;
#if USE_DOT2
      pk[(t << 1) + 0] = asu32(__builtin_amdgcn_cvt_pkrtz(u0, u1));
      pk[(t << 1) + 1] = asu32(__builtin_amdgcn_cvt_pkrtz(u2, u3));
#else
      { f16x2 a; a[0] = (__fp16)u0; a[1] = (__fp16)u1; pk[(t << 1) + 0] = asu32(a); }
      { f16x2 b; b[0] = (__fp16)u2; b[1] = (__fp16)u3; pk[(t << 1) + 1] = asu32(b); }
#endif
    }
    const int col = (g << 10) + cb;            // addr = col*8, 16B-aligned
    *(uint4*)&wts2[col][0]     = make_uint4(pk[0], pk[1], pk[2], pk[3]);
    *(uint4*)&wts2[col + 2][0] = make_uint4(pk[4], pk[5], pk[6], pk[7]);
  }
  // exact integer denominators: wave-reduce then cross-wave sum
#pragma unroll
  for (int s = 1; s < 64; s <<= 1) {
    id0 += __shfl_xor(id0, s); id1 += __shfl_xor(id1, s);
    id2 += __shfl_xor(id2, s); id3 += __shfl_xor(id3, s);
  }
  if (lane == 0) *(uint4*)&dred[wv][0] = make_uint4(id0, id1, id2, id3);
  __syncthreads();  // wts2 + dred visible to all
  const float dnm0 = (float)(dred[0][0] + dred[1][0] + dred[2][0] + dred[3][0]);
  const float dnm1 = (float)(dred[0][1] + dred[1][1] + dred[2][1] + dred[3][1]);
  const float dnm2 = (float)(dred[0][2] + dred[1][2] + dred[2][2] + dred[3][2]);
  const float dnm3 = (float)(dred[0][3] + dred[1][3] + dred[2][3] + dred[3][3]);

  // phase 5: PV via pk_fma, d-octet x 16 m-group partition (convert-once
  // fp16 operands; splats via shufflevector -> op_sel). Wave wv covers m
  // in [wv*1024, +1024): slot5 = lane&3 owns d [slot5*8, +8); mg = lane>>2
  // owns m stride 16. 64 iters x {1 ds_read_b64 (16 distinct m x 8B =
  // all banks, conflict-free) + 1 b128 V load (wave: 1KB contiguous) +
  // 16 pk_fma}.
  const int slot5 = lane & 3, mg = lane >> 2;
  const int mbase = wv << 10;
  f16x2 av2[4][4];   // [row][d-pair within octet]
#pragma unroll
  for (int r = 0; r < 4; ++r)
#pragma unroll
    for (int c = 0; c < 4; ++c) { av2[r][c][0] = (__fp16)0.f; av2[r][c][1] = (__fp16)0.f; }

#pragma unroll 4
  for (int ii = 0; ii < 64; ++ii) {
    const int m = mbase + (ii << 4) + mg;
    const f16x4v wq = *(const f16x4v*)&wts2[m][0];       // w0,w1,w2,w3
    const f16x8v vv = *(const f16x8v*)(Vh + m * HD + (slot5 << 3));
    const f16x2 va = __builtin_shufflevector(vv, vv, 0, 1);
    const f16x2 vb = __builtin_shufflevector(vv, vv, 2, 3);
    const f16x2 vc = __builtin_shufflevector(vv, vv, 4, 5);
    const f16x2 vd = __builtin_shufflevector(vv, vv, 6, 7);
    const f16x2 w00 = __builtin_shufflevector(wq, wq, 0, 0);
    const f16x2 w11 = __builtin_shufflevector(wq, wq, 1, 1);
    const f16x2 w22 = __builtin_shufflevector(wq, wq, 2, 2);
    const f16x2 w33 = __builtin_shufflevector(wq, wq, 3, 3);
    av2[0][0] += w00 * va; av2[0][1] += w00 * vb;
    av2[0][2] += w00 * vc; av2[0][3] += w00 * vd;
    av2[1][0] += w11 * va; av2[1][1] += w11 * vb;
    av2[1][2] += w11 * vc; av2[1][3] += w11 * vd;
    av2[2][0] += w22 * va; av2[2][1] += w22 * vb;
    av2[2][2] += w22 * vc; av2[2][3] += w22 * vd;
    av2[3][0] += w33 * va; av2[3][1] += w33 * vb;
    av2[3][2] += w33 * vc; av2[3][3] += w33 * vd;
  }
  // convert to fp32 and reduce over mg (lane bits 2..5)
  float av[4][8];
#pragma unroll
  for (int r = 0; r < 4; ++r)
#pragma unroll
    for (int c = 0; c < 4; ++c) {
      av[r][(c << 1) + 0] = (float)av2[r][c][0];
      av[r][(c << 1) + 1] = (float)av2[r][c][1];
    }
#pragma unroll
  for (int r = 0; r < 4; ++r)
#pragma unroll
    for (int c = 0; c < 8; ++c) {
      float x = av[r][c];
      x += __shfl_xor(x, 4); x += __shfl_xor(x, 8);
      x += __shfl_xor(x, 16); x += __shfl_xor(x, 32);
      av[r][c] = x;
    }
  if (mg == 0) {
#pragma unroll
    for (int r = 0; r < 4; ++r)
#pragma unroll
      for (int c = 0; c < 8; ++c)
        pvred[(((wv << 2) + slot5) * 4 + r) * 8 + c] = av[r][c];
  }
  __syncthreads();

  if (tid < 128) {
    const int r = tid >> 5, d = tid & 31;
    const int sl = d >> 3, c = d & 7;
    float val = 0.f;
#pragma unroll
    for (int w = 0; w < 4; ++w) val += pvred[(((w << 2) + sl) * 4 + r) * 8 + c];
    float dn = (r == 0) ? dnm0 : (r == 1) ? dnm1 : (r == 2) ? dnm2 : dnm3;
    val /= dn;
    AO[(head * HD + d) * NTOK + n0 + r] = val;  // [C][N] for proj GEMM
  }
}

// ---- kernel 5: GroupNorm stats (32 groups of 8 ch x 4096 = 32768 vals) ----

__global__ __launch_bounds__(256) void gn_stats(const float* __restrict__ O,
                                                float* __restrict__ ST) {
  const int g = blockIdx.x, tid = threadIdx.x;
  const float4* p4 = (const float4*)(O + g * 32768);
  float s = 0.f, ss = 0.f;
  for (int i = tid; i < 8192; i += 256) {
    float4 v = p4[i];
    s += (v.x + v.y) + (v.z + v.w);
    ss += (v.x * v.x + v.y * v.y) + (v.z * v.z + v.w * v.w);
  }
#pragma unroll
  for (int m = 1; m < 64; m <<= 1) {
    s += __shfl_xor(s, m);
    ss += __shfl_xor(ss, m);
  }
  __shared__ float rs[4], rss[4];
  if ((tid & 63) == 0) { rs[tid >> 6] = s; rss[tid >> 6] = ss; }
  __syncthreads();
  if (tid == 0) {
    float S = rs[0] + rs[1] + rs[2] + rs[3];
    float SS = rss[0] + rss[1] + rss[2] + rss[3];
    float mean = S * (1.f / 32768.f);
    float var = SS * (1.f / 32768.f) - mean * mean;
    ST[g * 2] = mean;
    ST[g * 2 + 1] = rsqrtf(var + 1e-6f);
  }
}

// ---- kernel 6: GroupNorm apply (in place on d_out) ------------------------
// Indexes FLOAT4s: total 1048576/4 = 262144 -> grid 1024 x 256.

__global__ __launch_bounds__(256) void gn_apply(float* __restrict__ O,
                                                const float* __restrict__ ST,
                                                const float* __restrict__ gamma,
                                                const float* __restrict__ beta) {
  const int i4 = blockIdx.x * 256 + threadIdx.x;  // float4 index
  const int c = i4 >> 10, g = c >> 3;
  const float a = ST[g * 2 + 1] * gamma[c];
  const float b = beta[c] - ST[g * 2] * a;
  float4 v = *(float4*)(O + (i4 << 2));
  v.x = v.x * a + b; v.y = v.y * a + b; v.z = v.z * a + b; v.w = v.w * a + b;
  *(float4*)(O + (i4 << 2)) = v;
}

// ---- launch ---------------------------------------------------------------

extern "C" void kernel_launch(void* const* d_in, const int* in_sizes, int n_in,
                              void* d_out, int out_size, void* d_ws,
                              size_t ws_size, hipStream_t stream) {
  const float* x = (const float*)d_in[0];       // [256][4096]
  const float* w_qkv = (const float*)d_in[1];   // [768][256]
  const float* w_proj = (const float*)d_in[2];  // [256][256]
  const float* gamma = (const float*)d_in[3];   // [256]
  const float* beta = (const float*)d_in[4];    // [256]
  float* out = (float*)d_out;                   // [256][4096]

  float* Q = (float*)d_ws;          // [8][4096][32] fp32
  float* KT = Q + 1048576;          // [8][32][4096] fp32 -> fp16 pairs in place
  float* V16r = KT + 1048576;       // [8][4096][32] FP16 (2MB of the 4MB slot)
  float* AO = V16r + 1048576;       // [256][4096] fp32
  float* ST = AO + 1048576;         // [32][2]

  gemm_k256<true><<<dim3(64, 12), 256, 0, stream>>>(w_qkv, x, Q, KT, V16r);
  l2norm_kt_pack<<<dim3(16, 8), 256, 0, stream>>>(KT);
  attn_kernel<<<8192, 256, 0, stream>>>(Q, KT, (const __fp16*)V16r, AO);
  gemm_k256<false><<<dim3(64, 4), 256, 0, stream>>>(w_proj, AO, out, nullptr, nullptr);
  gn_stats<<<32, 256, 0, stream>>>(out, ST);
  gn_apply<<<1024, 256, 0, stream>>>(out, ST, gamma, beta);
}